// Round 12
// baseline (374.566 us; speedup 1.0000x reference)
//
#include <hip/hip_runtime.h>
#include <math.h>

#define NN 20000
#define EE 320000
#define ETOT (EE + NN)
#define NEG 0.2f

typedef unsigned short ushortT;
typedef __attribute__((ext_vector_type(8))) short short8v;       // 8 bf16 (4 VGPRs)
typedef __attribute__((ext_vector_type(8))) unsigned short u16x8;
typedef __attribute__((ext_vector_type(4))) float f32x4;

// ---------- helpers ----------
__device__ __forceinline__ ushortT f2b(float f){            // fp32 -> bf16 (RNE)
  unsigned u = __float_as_uint(f);
  u += 0x7FFFu + ((u >> 16) & 1u);
  return (ushortT)(u >> 16);
}
__device__ __forceinline__ float b2f(ushortT b){
  return __uint_as_float(((unsigned)b) << 16);
}

// ---------- conversions ----------
__global__ void k_cvt(const float* __restrict__ in, ushortT* __restrict__ outp, int n4){
  int i = blockIdx.x*blockDim.x + threadIdx.x;
  if(i < n4){
    float4 v = *reinterpret_cast<const float4*>(in + (size_t)i*4);
    ushort4 o;
    o.x = f2b(v.x); o.y = f2b(v.y); o.z = f2b(v.z); o.w = f2b(v.w);
    *reinterpret_cast<ushort4*>(outp + (size_t)i*4) = o;
  }
}

// W[k][n] 512x512 fp32 -> Wt[n][k] bf16
__global__ void k_wtrans(const float* __restrict__ W, ushortT* __restrict__ Wt){
  __shared__ float t[32][33];
  int bk = blockIdx.x*32, bn = blockIdx.y*32;
  int tx = threadIdx.x & 31, ty = threadIdx.x >> 5;
  for(int r=0;r<32;r+=8)
    t[ty+r][tx] = W[(size_t)(bk+ty+r)*512 + bn+tx];
  __syncthreads();
  for(int r=0;r<32;r+=8)
    Wt[(size_t)(bn+ty+r)*512 + bk+tx] = f2b(t[tx][ty+r]);
}

// W3[512][40] fp32 -> Wt3p packed bf16 [64 kslots][48 rows][8], zero-padded rows 40..47
__global__ void k_wtrans3(const float* __restrict__ W3, ushortT* __restrict__ Wt3p){
  int idx = blockIdx.x*blockDim.x + threadIdx.x;
  if(idx >= 64*48*8) return;
  int kslot = idx / 384;
  int rem = idx - kslot*384;
  int n = rem >> 3;
  int jj = rem & 7;
  int k = kslot*8 + jj;
  float v = (n < 40) ? W3[(size_t)k*40 + n] : 0.f;
  Wt3p[idx] = f2b(v);
}

// ---------- CSR build ----------
__global__ void k_count(const int* __restrict__ edst, int* __restrict__ counts){
  int e = blockIdx.x*blockDim.x + threadIdx.x;
  if(e < ETOT){
    int d = (e < EE) ? edst[e] : (e - EE);
    atomicAdd(&counts[d], 1);
  }
}

__global__ void k_scan(const int* __restrict__ counts, int* __restrict__ rowstart){
  __shared__ int lds[1024];
  int tid = threadIdx.x;
  int base = tid*20;
  int s = 0;
  for(int j=0;j<20;j++){ int i=base+j; if(i<NN) s += counts[i]; }
  lds[tid] = s; __syncthreads();
  for(int off=1; off<1024; off<<=1){
    int v = (tid>=off) ? lds[tid-off] : 0;
    __syncthreads();
    lds[tid] += v;
    __syncthreads();
  }
  int run = lds[tid] - s;
  for(int j=0;j<20;j++){
    int i = base+j;
    if(i <= NN){
      rowstart[i] = run;
      if(i < NN) run += counts[i];
    }
  }
}

__global__ void k_fill(const int* __restrict__ esrc, const int* __restrict__ edst,
                       const int* __restrict__ rowstart,
                       int* __restrict__ cursor, int* __restrict__ srcs,
                       int* __restrict__ edsts){
  int e = blockIdx.x*blockDim.x + threadIdx.x;
  if(e < ETOT){
    int d = (e < EE) ? edst[e] : (e - EE);
    int s = (e < EE) ? esrc[e] : (e - EE);
    int pos = rowstart[d] + atomicAdd(&cursor[d], 1);
    srcs[pos] = s;
    edsts[pos] = d;
  }
}

// ---------- degree-sort (counting sort, 64 bins) ----------
__global__ void k_dhist(const int* __restrict__ counts, int* __restrict__ dhist){
  int d = blockIdx.x*blockDim.x + threadIdx.x;
  if(d < NN){
    int b = counts[d]; if(b > 63) b = 63;
    atomicAdd(&dhist[b], 1);
  }
}
__global__ void k_dscan(const int* __restrict__ dhist, int* __restrict__ dbase){
  int t = threadIdx.x;          // 64 threads, one wave
  int v = dhist[t];
  int sum = v;
  for(int off=1; off<64; off<<=1){
    int u = __shfl_up(sum, off);
    if(t >= off) sum += u;
  }
  dbase[t] = sum - v;           // exclusive prefix
}
__global__ void k_dscatter(const int* __restrict__ counts, const int* __restrict__ dbase,
                           int* __restrict__ dcur, int* __restrict__ dorder){
  int d = blockIdx.x*blockDim.x + threadIdx.x;
  if(d < NN){
    int b = counts[d]; if(b > 63) b = 63;
    int pos = dbase[b] + atomicAdd(&dcur[b], 1);
    dorder[pos] = d;
  }
}

// ---------- bf16 MFMA GEMM: C[M,512] = A[M,512] @ Bt[512,512]^T, bf16 out ----------
__global__ __launch_bounds__(256) void k_gemm_bf16(
    const ushortT* __restrict__ A, const ushortT* __restrict__ Bt,
    ushortT* __restrict__ Cb, int M)
{
  const int K = 512;
  __shared__ __align__(16) ushortT As[128*32];
  __shared__ __align__(16) ushortT Bs[128*32];
  int bm = blockIdx.x*128, bn = blockIdx.y*128;
  int tid = threadIdx.x, wave = tid>>6, lane = tid&63;
  int wm = (wave>>1)*64, wn = (wave&1)*64;
  f32x4 acc[4][4] = {};

  int l4 = lane>>2;
  int s4 = lane&3;
  int src_slot = s4 ^ (l4 & 3);     // XOR swizzle (both-sides involution)
  int r16 = lane&15, kg = lane>>4;

  for(int k0=0;k0<K;k0+=32){
    #pragma unroll
    for(int c=0;c<2;c++){
      int chunk = wave*2 + c;
      int arow = bm + chunk*16 + l4; if(arow > M-1) arow = M-1;
      const ushortT* ga = A + (size_t)arow*K + k0 + src_slot*8;
      __builtin_amdgcn_global_load_lds(
          (const __attribute__((address_space(1))) void*)ga,
          (__attribute__((address_space(3))) void*)(As + chunk*16*32), 16, 0, 0);
      int brow = bn + chunk*16 + l4;
      const ushortT* gb = Bt + (size_t)brow*K + k0 + src_slot*8;
      __builtin_amdgcn_global_load_lds(
          (const __attribute__((address_space(1))) void*)gb,
          (__attribute__((address_space(3))) void*)(Bs + chunk*16*32), 16, 0, 0);
    }
    asm volatile("s_waitcnt vmcnt(0)");
    __syncthreads();

    short8v a_frag[4], b_frag[4];
    #pragma unroll
    for(int i=0;i<4;i++){
      int row = wm + i*16 + r16;
      a_frag[i] = *reinterpret_cast<const short8v*>(As + row*32 + ((kg ^ (row&3))<<3));
    }
    #pragma unroll
    for(int j=0;j<4;j++){
      int row = wn + j*16 + r16;
      b_frag[j] = *reinterpret_cast<const short8v*>(Bs + row*32 + ((kg ^ (row&3))<<3));
    }
    #pragma unroll
    for(int i=0;i<4;i++)
      #pragma unroll
      for(int j=0;j<4;j++)
        acc[i][j] = __builtin_amdgcn_mfma_f32_16x16x32_bf16(a_frag[i], b_frag[j], acc[i][j], 0, 0, 0);
    __syncthreads();
  }

  // C/D layout: col = lane&15, row = (lane>>4)*4 + reg
  #pragma unroll
  for(int i=0;i<4;i++){
    #pragma unroll
    for(int j=0;j<4;j++){
      #pragma unroll
      for(int r=0;r<4;r++){
        int row = bm + wm + i*16 + kg*4 + r;
        int col = bn + wn + j*16 + r16;
        if(row < M) Cb[(size_t)row*512 + col] = f2b(acc[i][j][r]);
      }
    }
  }
}

// ---------- layer-3 MFMA GEMM: h3b[M,40] bf16 = A[M,512] @ W3; B resident in LDS ----------
__global__ __launch_bounds__(256) void k_gemm3m(const ushortT* __restrict__ A,
                                                const ushortT* __restrict__ Wt3p,
                                                ushortT* __restrict__ Cb, int M){
  const int K = 512;
  __shared__ __align__(16) ushortT As[128*32];      // 8 KB
  __shared__ __align__(16) ushortT Bs[64*48*8];     // 48 KB, [kslot][n][8]
  int bm = blockIdx.x*128;
  int tid = threadIdx.x, wave = tid>>6, lane = tid&63;

  // stage entire packed B once
  #pragma unroll
  for(int it=0; it<12; it++){
    int o = (it*256 + tid)*8;
    *reinterpret_cast<u16x8*>(Bs + o) = *reinterpret_cast<const u16x8*>(Wt3p + o);
  }

  int l4 = lane>>2, s4 = lane&3;
  int src_slot = s4 ^ (l4 & 3);
  int r16 = lane&15, kg = lane>>4;
  f32x4 acc[2][3] = {};

  for(int k0=0;k0<K;k0+=32){
    #pragma unroll
    for(int c=0;c<2;c++){
      int chunk = wave*2 + c;
      int arow = bm + chunk*16 + l4; if(arow > M-1) arow = M-1;
      const ushortT* ga = A + (size_t)arow*K + k0 + src_slot*8;
      __builtin_amdgcn_global_load_lds(
          (const __attribute__((address_space(1))) void*)ga,
          (__attribute__((address_space(3))) void*)(As + chunk*16*32), 16, 0, 0);
    }
    asm volatile("s_waitcnt vmcnt(0)");
    __syncthreads();

    short8v a_frag[2], b_frag[3];
    #pragma unroll
    for(int i=0;i<2;i++){
      int row = wave*32 + i*16 + r16;
      a_frag[i] = *reinterpret_cast<const short8v*>(As + row*32 + ((kg ^ (row&3))<<3));
    }
    int kslot = (k0>>3) + kg;
    #pragma unroll
    for(int j=0;j<3;j++){
      b_frag[j] = *reinterpret_cast<const short8v*>(Bs + kslot*384 + (j*16 + r16)*8);
    }
    #pragma unroll
    for(int i=0;i<2;i++)
      #pragma unroll
      for(int j=0;j<3;j++)
        acc[i][j] = __builtin_amdgcn_mfma_f32_16x16x32_bf16(a_frag[i], b_frag[j], acc[i][j], 0, 0, 0);
    __syncthreads();
  }

  #pragma unroll
  for(int i=0;i<2;i++){
    #pragma unroll
    for(int j=0;j<3;j++){
      #pragma unroll
      for(int r=0;r<4;r++){
        int row = bm + wave*32 + i*16 + kg*4 + r;
        int col = j*16 + r16;
        if(row < M && col < 40) Cb[(size_t)row*40 + col] = f2b(acc[i][j][r]);
      }
    }
  }
}

// ---------- per-node attention coefficients, H=8 C=64 (bf16 features) ----------
__global__ void k_attn8(const ushortT* __restrict__ feat, const float* __restrict__ atts,
                        const float* __restrict__ attd, float* __restrict__ a_s,
                        float* __restrict__ a_d){
  int n = blockIdx.x*4 + (threadIdx.x>>6);
  int lane = threadIdx.x & 63;
  if(n >= NN) return;
  int c0 = lane*8;
  u16x8 v = *reinterpret_cast<const u16x8*>(feat + (size_t)n*512 + c0);
  float s1 = 0.f, s2 = 0.f;
  #pragma unroll
  for(int j=0;j<8;j++){
    float f = b2f((ushortT)v[j]);
    s1 += f*atts[c0+j];
    s2 += f*attd[c0+j];
  }
  #pragma unroll
  for(int off=1; off<8; off<<=1){
    s1 += __shfl_xor(s1, off);
    s2 += __shfl_xor(s2, off);
  }
  if((lane&7) == 0){
    int head = lane>>3;
    a_s[n*8+head] = s1;
    a_d[n*8+head] = s2;
  }
}

// bf16 features, H=1 C=40 (layer 3)
__global__ void k_attn1b(const ushortT* __restrict__ feat, const float* __restrict__ atts,
                         const float* __restrict__ attd, float* __restrict__ a_s,
                         float* __restrict__ a_d){
  int n = blockIdx.x*4 + (threadIdx.x>>6);
  int lane = threadIdx.x & 63;
  if(n >= NN) return;
  float s1 = 0.f, s2 = 0.f;
  if(lane < 40){
    float v = b2f(feat[(size_t)n*40 + lane]);
    s1 = v*atts[lane];
    s2 = v*attd[lane];
  }
  for(int off=32; off; off>>=1){
    s1 += __shfl_xor(s1, off);
    s2 += __shfl_xor(s2, off);
  }
  if(lane == 0){ a_s[n] = s1; a_d[n] = s2; }
}

// ---------- edge precompute: per CSR pos, all 8 heads' alpha (f32 planes) ----------
__global__ void k_edge_pre(const int* __restrict__ srcs, const int* __restrict__ edsts,
                           const float* __restrict__ a_s, const float* __restrict__ a_d,
                           float* __restrict__ ap){
  int pos = blockIdx.x*blockDim.x + threadIdx.x;
  if(pos >= ETOT) return;
  int s = srcs[pos], d = edsts[pos];
  float4 s0 = *reinterpret_cast<const float4*>(a_s + ((size_t)s<<3));
  float4 s1 = *reinterpret_cast<const float4*>(a_s + ((size_t)s<<3) + 4);
  float4 d0 = *reinterpret_cast<const float4*>(a_d + ((size_t)d<<3));
  float4 d1 = *reinterpret_cast<const float4*>(a_d + ((size_t)d<<3) + 4);
  float l[8] = { s0.x+d0.x, s0.y+d0.y, s0.z+d0.z, s0.w+d0.w,
                 s1.x+d1.x, s1.y+d1.y, s1.z+d1.z, s1.w+d1.w };
  #pragma unroll
  for(int h=0;h<8;h++){
    float al = __expf(fmaxf(l[h], NEG*l[h]));
    ap[(size_t)h*ETOT + pos] = al;
  }
}

// ---------- fused CSR aggregate (H=8,C=64), sliced + degree-sorted dsts ----------
// Block b: slice = b&7 (XCD via round-robin), 8 waves x 8 dsts = 64 dsts/block.
// Lane = ds*8+cg: lane exclusively owns (dst ds, 8 channels) -> NO shuffle epilogue.
// dsts assigned via degree-sorted dorder -> the 8 dsts of a wave have ~equal degree.
// 4-deep pipeline: 4 srcs + 4 alpha broadcasts + 4 feat gathers in flight.
__global__ __launch_bounds__(512) void k_agg512(const ushortT* __restrict__ feat,
    const float* __restrict__ ap, const int* __restrict__ rowstart,
    const int* __restrict__ srcs, const int* __restrict__ dorder,
    const float* __restrict__ bias, ushortT* __restrict__ outb){
  int slice = blockIdx.x & 7;
  int lane  = threadIdx.x & 63;
  int ds = lane>>3, cg = lane&7;
  int idx = (blockIdx.x>>3)*64 + (int)(threadIdx.x>>6)*8 + ds;
  bool dok = idx < NN;
  int d  = dok ? dorder[idx] : 0;
  int p  = dok ? rowstart[d]   : 0;
  int p1 = dok ? rowstart[d+1] : 0;
  const float* plane = ap + (size_t)slice*ETOT;
  unsigned cbase = ((unsigned)slice<<6) + ((unsigned)cg<<3);
  float acc[8] = {0.f,0.f,0.f,0.f,0.f,0.f,0.f,0.f};
  float dsum = 0.f;

  for(; p+4 <= p1; p += 4){
    int s0 = srcs[p],   s1 = srcs[p+1];
    int s2 = srcs[p+2], s3 = srcs[p+3];
    float al0 = plane[p],   al1 = plane[p+1];
    float al2 = plane[p+2], al3 = plane[p+3];
    u16x8 v0 = *reinterpret_cast<const u16x8*>(feat + (((unsigned)s0<<9) + cbase));
    u16x8 v1 = *reinterpret_cast<const u16x8*>(feat + (((unsigned)s1<<9) + cbase));
    u16x8 v2 = *reinterpret_cast<const u16x8*>(feat + (((unsigned)s2<<9) + cbase));
    u16x8 v3 = *reinterpret_cast<const u16x8*>(feat + (((unsigned)s3<<9) + cbase));
    dsum += al0 + al1 + al2 + al3;
    #pragma unroll
    for(int j=0;j<8;j++) acc[j] += al0*b2f((ushortT)v0[j]);
    #pragma unroll
    for(int j=0;j<8;j++) acc[j] += al1*b2f((ushortT)v1[j]);
    #pragma unroll
    for(int j=0;j<8;j++) acc[j] += al2*b2f((ushortT)v2[j]);
    #pragma unroll
    for(int j=0;j<8;j++) acc[j] += al3*b2f((ushortT)v3[j]);
  }
  // predicated tail (<=3 per dst)
  while(__any(p < p1)){
    bool valid = p < p1;
    int pc = valid ? p : 0;
    int s_ = srcs[pc];
    float al = valid ? plane[pc] : 0.f;
    u16x8 v = *reinterpret_cast<const u16x8*>(feat + (((unsigned)s_<<9) + cbase));
    dsum += al;
    #pragma unroll
    for(int j=0;j<8;j++) acc[j] += al*b2f((ushortT)v[j]);
    p++;
  }

  if(dok){
    float invd = 1.f/(dsum + 1e-16f);
    u16x8 ov;
    #pragma unroll
    for(int j=0;j<8;j++){
      float o = acc[j]*invd + bias[cbase+j];
      o = (o > 0.f) ? o : (__expf(o) - 1.f);
      ov[j] = f2b(o);
    }
    *reinterpret_cast<u16x8*>(outb + (size_t)d*512 + cbase) = ov;
  }
}

// ---------- layer-3 aggregate (H=1,C=40, bf16 feat) + bias + log_softmax ----------
__global__ void k_agg_l3(const ushortT* __restrict__ feat,
    const float* __restrict__ a_s, const float* __restrict__ a_d,
    const int* __restrict__ rowstart, const int* __restrict__ srcs,
    const float* __restrict__ bias, float* __restrict__ outp){
  int d = blockIdx.x;
  int lane = threadIdx.x;       // 64 threads
  bool act = lane < 40;
  int li = act ? lane : 0;
  float ad_v = a_d[d];
  float acc = 0.f, dsum = 0.f;
  int p0 = rowstart[d], p1 = rowstart[d+1];
  int p = p0;
  for(; p+4 <= p1; p += 4){
    int s0_ = srcs[p], s1_ = srcs[p+1], s2_ = srcs[p+2], s3_ = srcs[p+3];
    float l0 = a_s[s0_] + ad_v, l1 = a_s[s1_] + ad_v;
    float l2 = a_s[s2_] + ad_v, l3 = a_s[s3_] + ad_v;
    float v0 = b2f(feat[(size_t)s0_*40 + li]);
    float v1 = b2f(feat[(size_t)s1_*40 + li]);
    float v2 = b2f(feat[(size_t)s2_*40 + li]);
    float v3 = b2f(feat[(size_t)s3_*40 + li]);
    float al0 = __expf(fmaxf(l0, NEG*l0));
    float al1 = __expf(fmaxf(l1, NEG*l1));
    float al2 = __expf(fmaxf(l2, NEG*l2));
    float al3 = __expf(fmaxf(l3, NEG*l3));
    dsum += al0 + al1 + al2 + al3;
    acc += al0*v0 + al1*v1 + al2*v2 + al3*v3;
  }
  for(; p<p1; p++){
    int s_ = srcs[p];
    float l = a_s[s_] + ad_v;
    float al = __expf(fmaxf(l, NEG*l));
    dsum += al;
    acc += al*b2f(feat[(size_t)s_*40 + li]);
  }
  float invd = 1.f/(dsum + 1e-16f);
  float o = act ? (acc*invd + bias[lane]) : -1e30f;
  float m = o;
  for(int off=32; off; off>>=1) m = fmaxf(m, __shfl_xor(m, off));
  float e_ = act ? expf(o - m) : 0.f;
  float ssum = e_;
  for(int off=32; off; off>>=1) ssum += __shfl_xor(ssum, off);
  if(act) outp[(size_t)d*40 + lane] = o - m - logf(ssum);
}

extern "C" void kernel_launch(void* const* d_in, const int* in_sizes, int n_in,
                              void* d_out, int out_size, void* d_ws, size_t ws_size,
                              hipStream_t stream){
  const float* x   = (const float*)d_in[0];
  const int*   ei  = (const int*)d_in[1];
  const int*   esrc = ei;
  const int*   edst = ei + EE;
  const float* W1  = (const float*)d_in[2];
  const float* as1 = (const float*)d_in[3];
  const float* ad1 = (const float*)d_in[4];
  const float* b1  = (const float*)d_in[5];
  const float* W2  = (const float*)d_in[6];
  const float* as2 = (const float*)d_in[7];
  const float* ad2 = (const float*)d_in[8];
  const float* b2  = (const float*)d_in[9];
  const float* W3  = (const float*)d_in[10];
  const float* as3 = (const float*)d_in[11];
  const float* ad3 = (const float*)d_in[12];
  const float* b3  = (const float*)d_in[13];
  float* out = (float*)d_out;

  char* w = (char*)d_ws;
  size_t off = 0;
  auto alloc = [&](size_t bytes)->char*{
    char* p = w + off;
    off = (off + bytes + 255) & ~(size_t)255;
    return p;
  };
  ushortT*  xb   = (ushortT*)alloc((size_t)NN*512*2);
  ushortT*  fA   = (ushortT*)alloc((size_t)NN*512*2);
  ushortT*  fB   = (ushortT*)alloc((size_t)NN*512*2);
  ushortT*  h3b  = (ushortT*)alloc((size_t)NN*40*2);
  ushortT*  Wt1  = (ushortT*)alloc((size_t)512*512*2);
  ushortT*  Wt2  = (ushortT*)alloc((size_t)512*512*2);
  ushortT*  Wt3p = (ushortT*)alloc((size_t)64*48*8*2);
  float*    a_s  = (float*)alloc((size_t)NN*8*4);
  float*    a_d  = (float*)alloc((size_t)NN*8*4);
  float*    ap   = (float*)alloc((size_t)8*ETOT*4);
  int* rowstart  = (int*)alloc((size_t)(NN+1)*4);
  int* cursor    = (int*)alloc((size_t)NN*4);
  int* counts    = (int*)alloc((size_t)NN*4);
  int* srcs      = (int*)alloc((size_t)ETOT*4);
  int* edsts     = (int*)alloc((size_t)ETOT*4);
  int* dorder    = (int*)alloc((size_t)NN*4);
  int* dhist     = (int*)alloc((size_t)64*4);
  int* dbase     = (int*)alloc((size_t)64*4);
  int* dcur      = (int*)alloc((size_t)64*4);

  // ---- conversions (independent of CSR) ----
  k_cvt<<<(NN*512/4 + 255)/256, 256, 0, stream>>>(x, xb, NN*512/4);
  dim3 wt_grid(16, 16);
  k_wtrans<<<wt_grid, 256, 0, stream>>>(W1, Wt1);
  k_wtrans<<<wt_grid, 256, 0, stream>>>(W2, Wt2);
  k_wtrans3<<<(64*48*8 + 255)/256, 256, 0, stream>>>(W3, Wt3p);

  // ---- CSR build (dst-grouped) ----
  hipMemsetAsync(counts, 0, (size_t)NN*4, stream);
  hipMemsetAsync(cursor, 0, (size_t)NN*4, stream);
  hipMemsetAsync(dhist,  0, (size_t)64*4, stream);
  hipMemsetAsync(dcur,   0, (size_t)64*4, stream);
  k_count<<<(ETOT+255)/256, 256, 0, stream>>>(edst, counts);
  k_scan<<<1, 1024, 0, stream>>>(counts, rowstart);
  k_fill<<<(ETOT+255)/256, 256, 0, stream>>>(esrc, edst, rowstart, cursor, srcs, edsts);

  // ---- degree sort ----
  k_dhist<<<(NN+255)/256, 256, 0, stream>>>(counts, dhist);
  k_dscan<<<1, 64, 0, stream>>>(dhist, dbase);
  k_dscatter<<<(NN+255)/256, 256, 0, stream>>>(counts, dbase, dcur, dorder);

  dim3 mgrid((NN+127)/128, 4);
  int edge_blocks = (ETOT + 255)/256;
  int agg_blocks  = ((NN + 63)/64)*8;

  // ---- layer 1 ----
  k_gemm_bf16<<<mgrid, 256, 0, stream>>>(xb, Wt1, fA, NN);
  k_attn8<<<(NN+3)/4, 256, 0, stream>>>(fA, as1, ad1, a_s, a_d);
  k_edge_pre<<<edge_blocks, 256, 0, stream>>>(srcs, edsts, a_s, a_d, ap);
  k_agg512<<<agg_blocks, 512, 0, stream>>>(fA, ap, rowstart, srcs, dorder, b1, fB);

  // ---- layer 2 ----
  k_gemm_bf16<<<mgrid, 256, 0, stream>>>(fB, Wt2, fA, NN);
  k_attn8<<<(NN+3)/4, 256, 0, stream>>>(fA, as2, ad2, a_s, a_d);
  k_edge_pre<<<edge_blocks, 256, 0, stream>>>(srcs, edsts, a_s, a_d, ap);
  k_agg512<<<agg_blocks, 512, 0, stream>>>(fA, ap, rowstart, srcs, dorder, b2, fB);

  // ---- layer 3 ----
  k_gemm3m<<<(NN+127)/128, 256, 0, stream>>>(fB, Wt3p, h3b, NN);
  k_attn1b<<<(NN+3)/4, 256, 0, stream>>>(h3b, as3, ad3, a_s, a_d);
  k_agg_l3<<<NN, 64, 0, stream>>>(h3b, a_s, a_d, rowstart, srcs, b3, out);
}

// Round 13
// 266.730 us; speedup vs baseline: 1.4043x; 1.4043x over previous
//
#include <hip/hip_runtime.h>
#include <math.h>

#define NN 20000
#define EE 320000
#define ETOT (EE + NN)
#define NEG 0.2f

typedef unsigned short ushortT;
typedef __attribute__((ext_vector_type(8))) short short8v;       // 8 bf16 (4 VGPRs)
typedef __attribute__((ext_vector_type(8))) unsigned short u16x8;
typedef __attribute__((ext_vector_type(4))) float f32x4;

// ---------- helpers ----------
__device__ __forceinline__ ushortT f2b(float f){            // fp32 -> bf16 (RNE)
  unsigned u = __float_as_uint(f);
  u += 0x7FFFu + ((u >> 16) & 1u);
  return (ushortT)(u >> 16);
}
__device__ __forceinline__ float b2f(ushortT b){
  return __uint_as_float(((unsigned)b) << 16);
}

// ---------- conversions ----------
__global__ void k_cvt(const float* __restrict__ in, ushortT* __restrict__ outp, int n4){
  int i = blockIdx.x*blockDim.x + threadIdx.x;
  if(i < n4){
    float4 v = *reinterpret_cast<const float4*>(in + (size_t)i*4);
    ushort4 o;
    o.x = f2b(v.x); o.y = f2b(v.y); o.z = f2b(v.z); o.w = f2b(v.w);
    *reinterpret_cast<ushort4*>(outp + (size_t)i*4) = o;
  }
}

// W[k][n] 512x512 fp32 -> Wt[n][k] bf16
__global__ void k_wtrans(const float* __restrict__ W, ushortT* __restrict__ Wt){
  __shared__ float t[32][33];
  int bk = blockIdx.x*32, bn = blockIdx.y*32;
  int tx = threadIdx.x & 31, ty = threadIdx.x >> 5;
  for(int r=0;r<32;r+=8)
    t[ty+r][tx] = W[(size_t)(bk+ty+r)*512 + bn+tx];
  __syncthreads();
  for(int r=0;r<32;r+=8)
    Wt[(size_t)(bn+ty+r)*512 + bk+tx] = f2b(t[tx][ty+r]);
}

// W3[512][40] fp32 -> Wt3p packed bf16 [64 kslots][48 rows][8], zero-padded rows 40..47
__global__ void k_wtrans3(const float* __restrict__ W3, ushortT* __restrict__ Wt3p){
  int idx = blockIdx.x*blockDim.x + threadIdx.x;
  if(idx >= 64*48*8) return;
  int kslot = idx / 384;
  int rem = idx - kslot*384;
  int n = rem >> 3;
  int jj = rem & 7;
  int k = kslot*8 + jj;
  float v = (n < 40) ? W3[(size_t)k*40 + n] : 0.f;
  Wt3p[idx] = f2b(v);
}

// ---------- CSR build ----------
__global__ void k_count(const int* __restrict__ edst, int* __restrict__ counts){
  int e = blockIdx.x*blockDim.x + threadIdx.x;
  if(e < ETOT){
    int d = (e < EE) ? edst[e] : (e - EE);
    atomicAdd(&counts[d], 1);
  }
}

__global__ void k_scan(const int* __restrict__ counts, int* __restrict__ rowstart){
  __shared__ int lds[1024];
  int tid = threadIdx.x;
  int base = tid*20;
  int s = 0;
  for(int j=0;j<20;j++){ int i=base+j; if(i<NN) s += counts[i]; }
  lds[tid] = s; __syncthreads();
  for(int off=1; off<1024; off<<=1){
    int v = (tid>=off) ? lds[tid-off] : 0;
    __syncthreads();
    lds[tid] += v;
    __syncthreads();
  }
  int run = lds[tid] - s;
  for(int j=0;j<20;j++){
    int i = base+j;
    if(i <= NN){
      rowstart[i] = run;
      if(i < NN) run += counts[i];
    }
  }
}

__global__ void k_fill(const int* __restrict__ esrc, const int* __restrict__ edst,
                       const int* __restrict__ rowstart,
                       int* __restrict__ cursor, int* __restrict__ srcs,
                       int* __restrict__ edsts){
  int e = blockIdx.x*blockDim.x + threadIdx.x;
  if(e < ETOT){
    int d = (e < EE) ? edst[e] : (e - EE);
    int s = (e < EE) ? esrc[e] : (e - EE);
    int pos = rowstart[d] + atomicAdd(&cursor[d], 1);
    srcs[pos] = s;
    edsts[pos] = d;
  }
}

// ---------- degree-sort (counting sort, 64 bins, LDS-aggregated atomics) ----------
__global__ void k_dhist2(const int* __restrict__ counts, int* __restrict__ dhist){
  __shared__ int h[64];
  int t = threadIdx.x;
  if(t < 64) h[t] = 0;
  __syncthreads();
  int d = blockIdx.x*blockDim.x + t;
  if(d < NN){
    int b = counts[d]; if(b > 63) b = 63;
    atomicAdd(&h[b], 1);
  }
  __syncthreads();
  if(t < 64 && h[t]) atomicAdd(&dhist[t], h[t]);
}

__global__ void k_dscan(const int* __restrict__ dhist, int* __restrict__ dbase){
  int t = threadIdx.x;          // 64 threads, one wave
  int v = dhist[t];
  int sum = v;
  for(int off=1; off<64; off<<=1){
    int u = __shfl_up(sum, off);
    if(t >= off) sum += u;
  }
  dbase[t] = sum - v;           // exclusive prefix
}

__global__ void k_dscatter2(const int* __restrict__ counts, const int* __restrict__ dbase,
                            int* __restrict__ dcur, int* __restrict__ dorder){
  __shared__ int h[64];      // block-local bin counts
  __shared__ int gbase[64];  // reserved global offset per bin for this block
  __shared__ int rk[64];     // intra-block running rank per bin
  int t = threadIdx.x;
  if(t < 64){ h[t] = 0; rk[t] = 0; }
  __syncthreads();
  int d = blockIdx.x*blockDim.x + t;
  int b = -1;
  if(d < NN){
    b = counts[d]; if(b > 63) b = 63;
    atomicAdd(&h[b], 1);
  }
  __syncthreads();
  if(t < 64) gbase[t] = h[t] ? atomicAdd(&dcur[t], h[t]) : 0;
  __syncthreads();
  if(d < NN){
    int r = atomicAdd(&rk[b], 1);
    dorder[dbase[b] + gbase[b] + r] = d;
  }
}

// ---------- bf16 MFMA GEMM: C[M,512] = A[M,512] @ Bt[512,512]^T, bf16 out ----------
__global__ __launch_bounds__(256) void k_gemm_bf16(
    const ushortT* __restrict__ A, const ushortT* __restrict__ Bt,
    ushortT* __restrict__ Cb, int M)
{
  const int K = 512;
  __shared__ __align__(16) ushortT As[128*32];
  __shared__ __align__(16) ushortT Bs[128*32];
  int bm = blockIdx.x*128, bn = blockIdx.y*128;
  int tid = threadIdx.x, wave = tid>>6, lane = tid&63;
  int wm = (wave>>1)*64, wn = (wave&1)*64;
  f32x4 acc[4][4] = {};

  int l4 = lane>>2;
  int s4 = lane&3;
  int src_slot = s4 ^ (l4 & 3);     // XOR swizzle (both-sides involution)
  int r16 = lane&15, kg = lane>>4;

  for(int k0=0;k0<K;k0+=32){
    #pragma unroll
    for(int c=0;c<2;c++){
      int chunk = wave*2 + c;
      int arow = bm + chunk*16 + l4; if(arow > M-1) arow = M-1;
      const ushortT* ga = A + (size_t)arow*K + k0 + src_slot*8;
      __builtin_amdgcn_global_load_lds(
          (const __attribute__((address_space(1))) void*)ga,
          (__attribute__((address_space(3))) void*)(As + chunk*16*32), 16, 0, 0);
      int brow = bn + chunk*16 + l4;
      const ushortT* gb = Bt + (size_t)brow*K + k0 + src_slot*8;
      __builtin_amdgcn_global_load_lds(
          (const __attribute__((address_space(1))) void*)gb,
          (__attribute__((address_space(3))) void*)(Bs + chunk*16*32), 16, 0, 0);
    }
    asm volatile("s_waitcnt vmcnt(0)");
    __syncthreads();

    short8v a_frag[4], b_frag[4];
    #pragma unroll
    for(int i=0;i<4;i++){
      int row = wm + i*16 + r16;
      a_frag[i] = *reinterpret_cast<const short8v*>(As + row*32 + ((kg ^ (row&3))<<3));
    }
    #pragma unroll
    for(int j=0;j<4;j++){
      int row = wn + j*16 + r16;
      b_frag[j] = *reinterpret_cast<const short8v*>(Bs + row*32 + ((kg ^ (row&3))<<3));
    }
    #pragma unroll
    for(int i=0;i<4;i++)
      #pragma unroll
      for(int j=0;j<4;j++)
        acc[i][j] = __builtin_amdgcn_mfma_f32_16x16x32_bf16(a_frag[i], b_frag[j], acc[i][j], 0, 0, 0);
    __syncthreads();
  }

  // C/D layout: col = lane&15, row = (lane>>4)*4 + reg
  #pragma unroll
  for(int i=0;i<4;i++){
    #pragma unroll
    for(int j=0;j<4;j++){
      #pragma unroll
      for(int r=0;r<4;r++){
        int row = bm + wm + i*16 + kg*4 + r;
        int col = bn + wn + j*16 + r16;
        if(row < M) Cb[(size_t)row*512 + col] = f2b(acc[i][j][r]);
      }
    }
  }
}

// ---------- layer-3 MFMA GEMM: h3b[M,40] bf16 = A[M,512] @ W3; B resident in LDS ----------
__global__ __launch_bounds__(256) void k_gemm3m(const ushortT* __restrict__ A,
                                                const ushortT* __restrict__ Wt3p,
                                                ushortT* __restrict__ Cb, int M){
  const int K = 512;
  __shared__ __align__(16) ushortT As[128*32];      // 8 KB
  __shared__ __align__(16) ushortT Bs[64*48*8];     // 48 KB, [kslot][n][8]
  int bm = blockIdx.x*128;
  int tid = threadIdx.x, wave = tid>>6, lane = tid&63;

  // stage entire packed B once
  #pragma unroll
  for(int it=0; it<12; it++){
    int o = (it*256 + tid)*8;
    *reinterpret_cast<u16x8*>(Bs + o) = *reinterpret_cast<const u16x8*>(Wt3p + o);
  }

  int l4 = lane>>2, s4 = lane&3;
  int src_slot = s4 ^ (l4 & 3);
  int r16 = lane&15, kg = lane>>4;
  f32x4 acc[2][3] = {};

  for(int k0=0;k0<K;k0+=32){
    #pragma unroll
    for(int c=0;c<2;c++){
      int chunk = wave*2 + c;
      int arow = bm + chunk*16 + l4; if(arow > M-1) arow = M-1;
      const ushortT* ga = A + (size_t)arow*K + k0 + src_slot*8;
      __builtin_amdgcn_global_load_lds(
          (const __attribute__((address_space(1))) void*)ga,
          (__attribute__((address_space(3))) void*)(As + chunk*16*32), 16, 0, 0);
    }
    asm volatile("s_waitcnt vmcnt(0)");
    __syncthreads();

    short8v a_frag[2], b_frag[3];
    #pragma unroll
    for(int i=0;i<2;i++){
      int row = wave*32 + i*16 + r16;
      a_frag[i] = *reinterpret_cast<const short8v*>(As + row*32 + ((kg ^ (row&3))<<3));
    }
    int kslot = (k0>>3) + kg;
    #pragma unroll
    for(int j=0;j<3;j++){
      b_frag[j] = *reinterpret_cast<const short8v*>(Bs + kslot*384 + (j*16 + r16)*8);
    }
    #pragma unroll
    for(int i=0;i<2;i++)
      #pragma unroll
      for(int j=0;j<3;j++)
        acc[i][j] = __builtin_amdgcn_mfma_f32_16x16x32_bf16(a_frag[i], b_frag[j], acc[i][j], 0, 0, 0);
    __syncthreads();
  }

  #pragma unroll
  for(int i=0;i<2;i++){
    #pragma unroll
    for(int j=0;j<3;j++){
      #pragma unroll
      for(int r=0;r<4;r++){
        int row = bm + wave*32 + i*16 + kg*4 + r;
        int col = j*16 + r16;
        if(row < M && col < 40) Cb[(size_t)row*40 + col] = f2b(acc[i][j][r]);
      }
    }
  }
}

// ---------- per-node attention coefficients, H=8 C=64 (bf16 features) ----------
__global__ void k_attn8(const ushortT* __restrict__ feat, const float* __restrict__ atts,
                        const float* __restrict__ attd, float* __restrict__ a_s,
                        float* __restrict__ a_d){
  int n = blockIdx.x*4 + (threadIdx.x>>6);
  int lane = threadIdx.x & 63;
  if(n >= NN) return;
  int c0 = lane*8;
  u16x8 v = *reinterpret_cast<const u16x8*>(feat + (size_t)n*512 + c0);
  float s1 = 0.f, s2 = 0.f;
  #pragma unroll
  for(int j=0;j<8;j++){
    float f = b2f((ushortT)v[j]);
    s1 += f*atts[c0+j];
    s2 += f*attd[c0+j];
  }
  #pragma unroll
  for(int off=1; off<8; off<<=1){
    s1 += __shfl_xor(s1, off);
    s2 += __shfl_xor(s2, off);
  }
  if((lane&7) == 0){
    int head = lane>>3;
    a_s[n*8+head] = s1;
    a_d[n*8+head] = s2;
  }
}

// bf16 features, H=1 C=40 (layer 3)
__global__ void k_attn1b(const ushortT* __restrict__ feat, const float* __restrict__ atts,
                         const float* __restrict__ attd, float* __restrict__ a_s,
                         float* __restrict__ a_d){
  int n = blockIdx.x*4 + (threadIdx.x>>6);
  int lane = threadIdx.x & 63;
  if(n >= NN) return;
  float s1 = 0.f, s2 = 0.f;
  if(lane < 40){
    float v = b2f(feat[(size_t)n*40 + lane]);
    s1 = v*atts[lane];
    s2 = v*attd[lane];
  }
  for(int off=32; off; off>>=1){
    s1 += __shfl_xor(s1, off);
    s2 += __shfl_xor(s2, off);
  }
  if(lane == 0){ a_s[n] = s1; a_d[n] = s2; }
}

// ---------- edge precompute: per CSR pos, all 8 heads' alpha (f32 planes) ----------
__global__ void k_edge_pre(const int* __restrict__ srcs, const int* __restrict__ edsts,
                           const float* __restrict__ a_s, const float* __restrict__ a_d,
                           float* __restrict__ ap){
  int pos = blockIdx.x*blockDim.x + threadIdx.x;
  if(pos >= ETOT) return;
  int s = srcs[pos], d = edsts[pos];
  float4 s0 = *reinterpret_cast<const float4*>(a_s + ((size_t)s<<3));
  float4 s1 = *reinterpret_cast<const float4*>(a_s + ((size_t)s<<3) + 4);
  float4 d0 = *reinterpret_cast<const float4*>(a_d + ((size_t)d<<3));
  float4 d1 = *reinterpret_cast<const float4*>(a_d + ((size_t)d<<3) + 4);
  float l[8] = { s0.x+d0.x, s0.y+d0.y, s0.z+d0.z, s0.w+d0.w,
                 s1.x+d1.x, s1.y+d1.y, s1.z+d1.z, s1.w+d1.w };
  #pragma unroll
  for(int h=0;h<8;h++){
    float al = __expf(fmaxf(l[h], NEG*l[h]));
    ap[(size_t)h*ETOT + pos] = al;
  }
}

// ---------- fused CSR aggregate (H=8,C=64), sliced + degree-sorted dsts ----------
// Block b: slice = b&7 (XCD via round-robin), 8 waves x 8 dsts = 64 dsts/block.
// Lane = ds*8+cg: lane exclusively owns (dst ds, 8 channels) -> NO shuffle epilogue.
// dsts assigned via degree-sorted dorder -> the 8 dsts of a wave have ~equal degree.
// 4-deep pipeline: 4 srcs + 4 alpha broadcasts + 4 feat gathers in flight.
__global__ __launch_bounds__(512) void k_agg512(const ushortT* __restrict__ feat,
    const float* __restrict__ ap, const int* __restrict__ rowstart,
    const int* __restrict__ srcs, const int* __restrict__ dorder,
    const float* __restrict__ bias, ushortT* __restrict__ outb){
  int slice = blockIdx.x & 7;
  int lane  = threadIdx.x & 63;
  int ds = lane>>3, cg = lane&7;
  int idx = (blockIdx.x>>3)*64 + (int)(threadIdx.x>>6)*8 + ds;
  bool dok = idx < NN;
  int d  = dok ? dorder[idx] : 0;
  int p  = dok ? rowstart[d]   : 0;
  int p1 = dok ? rowstart[d+1] : 0;
  const float* plane = ap + (size_t)slice*ETOT;
  unsigned cbase = ((unsigned)slice<<6) + ((unsigned)cg<<3);
  float acc[8] = {0.f,0.f,0.f,0.f,0.f,0.f,0.f,0.f};
  float dsum = 0.f;

  for(; p+4 <= p1; p += 4){
    int s0 = srcs[p],   s1 = srcs[p+1];
    int s2 = srcs[p+2], s3 = srcs[p+3];
    float al0 = plane[p],   al1 = plane[p+1];
    float al2 = plane[p+2], al3 = plane[p+3];
    u16x8 v0 = *reinterpret_cast<const u16x8*>(feat + (((unsigned)s0<<9) + cbase));
    u16x8 v1 = *reinterpret_cast<const u16x8*>(feat + (((unsigned)s1<<9) + cbase));
    u16x8 v2 = *reinterpret_cast<const u16x8*>(feat + (((unsigned)s2<<9) + cbase));
    u16x8 v3 = *reinterpret_cast<const u16x8*>(feat + (((unsigned)s3<<9) + cbase));
    dsum += al0 + al1 + al2 + al3;
    #pragma unroll
    for(int j=0;j<8;j++) acc[j] += al0*b2f((ushortT)v0[j]);
    #pragma unroll
    for(int j=0;j<8;j++) acc[j] += al1*b2f((ushortT)v1[j]);
    #pragma unroll
    for(int j=0;j<8;j++) acc[j] += al2*b2f((ushortT)v2[j]);
    #pragma unroll
    for(int j=0;j<8;j++) acc[j] += al3*b2f((ushortT)v3[j]);
  }
  // predicated tail (<=3 per dst)
  while(__any(p < p1)){
    bool valid = p < p1;
    int pc = valid ? p : 0;
    int s_ = srcs[pc];
    float al = valid ? plane[pc] : 0.f;
    u16x8 v = *reinterpret_cast<const u16x8*>(feat + (((unsigned)s_<<9) + cbase));
    dsum += al;
    #pragma unroll
    for(int j=0;j<8;j++) acc[j] += al*b2f((ushortT)v[j]);
    p++;
  }

  if(dok){
    float invd = 1.f/(dsum + 1e-16f);
    u16x8 ov;
    #pragma unroll
    for(int j=0;j<8;j++){
      float o = acc[j]*invd + bias[cbase+j];
      o = (o > 0.f) ? o : (__expf(o) - 1.f);
      ov[j] = f2b(o);
    }
    *reinterpret_cast<u16x8*>(outb + (size_t)d*512 + cbase) = ov;
  }
}

// ---------- layer-3 aggregate (H=1,C=40, bf16 feat) + bias + log_softmax ----------
__global__ void k_agg_l3(const ushortT* __restrict__ feat,
    const float* __restrict__ a_s, const float* __restrict__ a_d,
    const int* __restrict__ rowstart, const int* __restrict__ srcs,
    const float* __restrict__ bias, float* __restrict__ outp){
  int d = blockIdx.x;
  int lane = threadIdx.x;       // 64 threads
  bool act = lane < 40;
  int li = act ? lane : 0;
  float ad_v = a_d[d];
  float acc = 0.f, dsum = 0.f;
  int p0 = rowstart[d], p1 = rowstart[d+1];
  int p = p0;
  for(; p+4 <= p1; p += 4){
    int s0_ = srcs[p], s1_ = srcs[p+1], s2_ = srcs[p+2], s3_ = srcs[p+3];
    float l0 = a_s[s0_] + ad_v, l1 = a_s[s1_] + ad_v;
    float l2 = a_s[s2_] + ad_v, l3 = a_s[s3_] + ad_v;
    float v0 = b2f(feat[(size_t)s0_*40 + li]);
    float v1 = b2f(feat[(size_t)s1_*40 + li]);
    float v2 = b2f(feat[(size_t)s2_*40 + li]);
    float v3 = b2f(feat[(size_t)s3_*40 + li]);
    float al0 = __expf(fmaxf(l0, NEG*l0));
    float al1 = __expf(fmaxf(l1, NEG*l1));
    float al2 = __expf(fmaxf(l2, NEG*l2));
    float al3 = __expf(fmaxf(l3, NEG*l3));
    dsum += al0 + al1 + al2 + al3;
    acc += al0*v0 + al1*v1 + al2*v2 + al3*v3;
  }
  for(; p<p1; p++){
    int s_ = srcs[p];
    float l = a_s[s_] + ad_v;
    float al = __expf(fmaxf(l, NEG*l));
    dsum += al;
    acc += al*b2f(feat[(size_t)s_*40 + li]);
  }
  float invd = 1.f/(dsum + 1e-16f);
  float o = act ? (acc*invd + bias[lane]) : -1e30f;
  float m = o;
  for(int off=32; off; off>>=1) m = fmaxf(m, __shfl_xor(m, off));
  float e_ = act ? expf(o - m) : 0.f;
  float ssum = e_;
  for(int off=32; off; off>>=1) ssum += __shfl_xor(ssum, off);
  if(act) outp[(size_t)d*40 + lane] = o - m - logf(ssum);
}

extern "C" void kernel_launch(void* const* d_in, const int* in_sizes, int n_in,
                              void* d_out, int out_size, void* d_ws, size_t ws_size,
                              hipStream_t stream){
  const float* x   = (const float*)d_in[0];
  const int*   ei  = (const int*)d_in[1];
  const int*   esrc = ei;
  const int*   edst = ei + EE;
  const float* W1  = (const float*)d_in[2];
  const float* as1 = (const float*)d_in[3];
  const float* ad1 = (const float*)d_in[4];
  const float* b1  = (const float*)d_in[5];
  const float* W2  = (const float*)d_in[6];
  const float* as2 = (const float*)d_in[7];
  const float* ad2 = (const float*)d_in[8];
  const float* b2  = (const float*)d_in[9];
  const float* W3  = (const float*)d_in[10];
  const float* as3 = (const float*)d_in[11];
  const float* ad3 = (const float*)d_in[12];
  const float* b3  = (const float*)d_in[13];
  float* out = (float*)d_out;

  char* w = (char*)d_ws;
  size_t off = 0;
  auto alloc = [&](size_t bytes)->char*{
    char* p = w + off;
    off = (off + bytes + 255) & ~(size_t)255;
    return p;
  };
  ushortT*  xb   = (ushortT*)alloc((size_t)NN*512*2);
  ushortT*  fA   = (ushortT*)alloc((size_t)NN*512*2);
  ushortT*  fB   = (ushortT*)alloc((size_t)NN*512*2);
  ushortT*  h3b  = (ushortT*)alloc((size_t)NN*40*2);
  ushortT*  Wt1  = (ushortT*)alloc((size_t)512*512*2);
  ushortT*  Wt2  = (ushortT*)alloc((size_t)512*512*2);
  ushortT*  Wt3p = (ushortT*)alloc((size_t)64*48*8*2);
  float*    a_s  = (float*)alloc((size_t)NN*8*4);
  float*    a_d  = (float*)alloc((size_t)NN*8*4);
  float*    ap   = (float*)alloc((size_t)8*ETOT*4);
  int* rowstart  = (int*)alloc((size_t)(NN+1)*4);
  int* cursor    = (int*)alloc((size_t)NN*4);
  int* counts    = (int*)alloc((size_t)NN*4);
  int* srcs      = (int*)alloc((size_t)ETOT*4);
  int* edsts     = (int*)alloc((size_t)ETOT*4);
  int* dorder    = (int*)alloc((size_t)NN*4);
  int* dhist     = (int*)alloc((size_t)64*4);
  int* dbase     = (int*)alloc((size_t)64*4);
  int* dcur      = (int*)alloc((size_t)64*4);

  // ---- conversions (independent of CSR) ----
  k_cvt<<<(NN*512/4 + 255)/256, 256, 0, stream>>>(x, xb, NN*512/4);
  dim3 wt_grid(16, 16);
  k_wtrans<<<wt_grid, 256, 0, stream>>>(W1, Wt1);
  k_wtrans<<<wt_grid, 256, 0, stream>>>(W2, Wt2);
  k_wtrans3<<<(64*48*8 + 255)/256, 256, 0, stream>>>(W3, Wt3p);

  // ---- CSR build (dst-grouped) ----
  hipMemsetAsync(counts, 0, (size_t)NN*4, stream);
  hipMemsetAsync(cursor, 0, (size_t)NN*4, stream);
  hipMemsetAsync(dhist,  0, (size_t)64*4, stream);
  hipMemsetAsync(dcur,   0, (size_t)64*4, stream);
  k_count<<<(ETOT+255)/256, 256, 0, stream>>>(edst, counts);
  k_scan<<<1, 1024, 0, stream>>>(counts, rowstart);
  k_fill<<<(ETOT+255)/256, 256, 0, stream>>>(esrc, edst, rowstart, cursor, srcs, edsts);

  // ---- degree sort (LDS-aggregated counting sort) ----
  k_dhist2<<<(NN+255)/256, 256, 0, stream>>>(counts, dhist);
  k_dscan<<<1, 64, 0, stream>>>(dhist, dbase);
  k_dscatter2<<<(NN+255)/256, 256, 0, stream>>>(counts, dbase, dcur, dorder);

  dim3 mgrid((NN+127)/128, 4);
  int edge_blocks = (ETOT + 255)/256;
  int agg_blocks  = ((NN + 63)/64)*8;

  // ---- layer 1 ----
  k_gemm_bf16<<<mgrid, 256, 0, stream>>>(xb, Wt1, fA, NN);
  k_attn8<<<(NN+3)/4, 256, 0, stream>>>(fA, as1, ad1, a_s, a_d);
  k_edge_pre<<<edge_blocks, 256, 0, stream>>>(srcs, edsts, a_s, a_d, ap);
  k_agg512<<<agg_blocks, 512, 0, stream>>>(fA, ap, rowstart, srcs, dorder, b1, fB);

  // ---- layer 2 ----
  k_gemm_bf16<<<mgrid, 256, 0, stream>>>(fB, Wt2, fA, NN);
  k_attn8<<<(NN+3)/4, 256, 0, stream>>>(fA, as2, ad2, a_s, a_d);
  k_edge_pre<<<edge_blocks, 256, 0, stream>>>(srcs, edsts, a_s, a_d, ap);
  k_agg512<<<agg_blocks, 512, 0, stream>>>(fA, ap, rowstart, srcs, dorder, b2, fB);

  // ---- layer 3 ----
  k_gemm3m<<<(NN+127)/128, 256, 0, stream>>>(fB, Wt3p, h3b, NN);
  k_attn1b<<<(NN+3)/4, 256, 0, stream>>>(h3b, as3, ad3, a_s, a_d);
  k_agg_l3<<<NN, 64, 0, stream>>>(h3b, a_s, a_d, rowstart, srcs, b3, out);
}

// Round 14
// 240.148 us; speedup vs baseline: 1.5597x; 1.1107x over previous
//
#include <hip/hip_runtime.h>
#include <math.h>

#define NN 20000
#define EE 320000
#define ETOT (EE + NN)
#define NEG 0.2f

typedef unsigned short ushortT;
typedef __attribute__((ext_vector_type(8))) short short8v;       // 8 bf16 (4 VGPRs)
typedef __attribute__((ext_vector_type(8))) unsigned short u16x8;
typedef __attribute__((ext_vector_type(4))) float f32x4;

// ---------- helpers ----------
__device__ __forceinline__ ushortT f2b(float f){            // fp32 -> bf16 (RNE)
  unsigned u = __float_as_uint(f);
  u += 0x7FFFu + ((u >> 16) & 1u);
  return (ushortT)(u >> 16);
}
__device__ __forceinline__ float b2f(ushortT b){
  return __uint_as_float(((unsigned)b) << 16);
}

// ---------- conversions ----------
__global__ void k_cvt(const float* __restrict__ in, ushortT* __restrict__ outp, int n4){
  int i = blockIdx.x*blockDim.x + threadIdx.x;
  if(i < n4){
    float4 v = *reinterpret_cast<const float4*>(in + (size_t)i*4);
    ushort4 o;
    o.x = f2b(v.x); o.y = f2b(v.y); o.z = f2b(v.z); o.w = f2b(v.w);
    *reinterpret_cast<ushort4*>(outp + (size_t)i*4) = o;
  }
}

// W[k][n] 512x512 fp32 -> Wt[n][k] bf16
__global__ void k_wtrans(const float* __restrict__ W, ushortT* __restrict__ Wt){
  __shared__ float t[32][33];
  int bk = blockIdx.x*32, bn = blockIdx.y*32;
  int tx = threadIdx.x & 31, ty = threadIdx.x >> 5;
  for(int r=0;r<32;r+=8)
    t[ty+r][tx] = W[(size_t)(bk+ty+r)*512 + bn+tx];
  __syncthreads();
  for(int r=0;r<32;r+=8)
    Wt[(size_t)(bn+ty+r)*512 + bk+tx] = f2b(t[tx][ty+r]);
}

// W3[512][40] fp32 -> Wt3p packed bf16 [64 kslots][48 rows][8], zero-padded rows 40..47
__global__ void k_wtrans3(const float* __restrict__ W3, ushortT* __restrict__ Wt3p){
  int idx = blockIdx.x*blockDim.x + threadIdx.x;
  if(idx >= 64*48*8) return;
  int kslot = idx / 384;
  int rem = idx - kslot*384;
  int n = rem >> 3;
  int jj = rem & 7;
  int k = kslot*8 + jj;
  float v = (n < 40) ? W3[(size_t)k*40 + n] : 0.f;
  Wt3p[idx] = f2b(v);
}

// ---------- CSR build ----------
__global__ void k_count(const int* __restrict__ edst, int* __restrict__ counts){
  int e = blockIdx.x*blockDim.x + threadIdx.x;
  if(e < ETOT){
    int d = (e < EE) ? edst[e] : (e - EE);
    atomicAdd(&counts[d], 1);
  }
}

__global__ void k_scan(const int* __restrict__ counts, int* __restrict__ rowstart){
  __shared__ int lds[1024];
  int tid = threadIdx.x;
  int base = tid*20;
  int s = 0;
  for(int j=0;j<20;j++){ int i=base+j; if(i<NN) s += counts[i]; }
  lds[tid] = s; __syncthreads();
  for(int off=1; off<1024; off<<=1){
    int v = (tid>=off) ? lds[tid-off] : 0;
    __syncthreads();
    lds[tid] += v;
    __syncthreads();
  }
  int run = lds[tid] - s;
  for(int j=0;j<20;j++){
    int i = base+j;
    if(i <= NN){
      rowstart[i] = run;
      if(i < NN) run += counts[i];
    }
  }
}

__global__ void k_fill(const int* __restrict__ esrc, const int* __restrict__ edst,
                       const int* __restrict__ rowstart,
                       int* __restrict__ cursor, int* __restrict__ srcs,
                       int* __restrict__ edsts){
  int e = blockIdx.x*blockDim.x + threadIdx.x;
  if(e < ETOT){
    int d = (e < EE) ? edst[e] : (e - EE);
    int s = (e < EE) ? esrc[e] : (e - EE);
    int pos = rowstart[d] + atomicAdd(&cursor[d], 1);
    srcs[pos] = s;
    edsts[pos] = d;
  }
}

// ---------- bf16 MFMA GEMM: C[M,512] = A[M,512] @ Bt[512,512]^T, bf16 out ----------
__global__ __launch_bounds__(256) void k_gemm_bf16(
    const ushortT* __restrict__ A, const ushortT* __restrict__ Bt,
    ushortT* __restrict__ Cb, int M)
{
  const int K = 512;
  __shared__ __align__(16) ushortT As[128*32];
  __shared__ __align__(16) ushortT Bs[128*32];
  int bm = blockIdx.x*128, bn = blockIdx.y*128;
  int tid = threadIdx.x, wave = tid>>6, lane = tid&63;
  int wm = (wave>>1)*64, wn = (wave&1)*64;
  f32x4 acc[4][4] = {};

  int l4 = lane>>2;
  int s4 = lane&3;
  int src_slot = s4 ^ (l4 & 3);     // XOR swizzle (both-sides involution)
  int r16 = lane&15, kg = lane>>4;

  for(int k0=0;k0<K;k0+=32){
    #pragma unroll
    for(int c=0;c<2;c++){
      int chunk = wave*2 + c;
      int arow = bm + chunk*16 + l4; if(arow > M-1) arow = M-1;
      const ushortT* ga = A + (size_t)arow*K + k0 + src_slot*8;
      __builtin_amdgcn_global_load_lds(
          (const __attribute__((address_space(1))) void*)ga,
          (__attribute__((address_space(3))) void*)(As + chunk*16*32), 16, 0, 0);
      int brow = bn + chunk*16 + l4;
      const ushortT* gb = Bt + (size_t)brow*K + k0 + src_slot*8;
      __builtin_amdgcn_global_load_lds(
          (const __attribute__((address_space(1))) void*)gb,
          (__attribute__((address_space(3))) void*)(Bs + chunk*16*32), 16, 0, 0);
    }
    asm volatile("s_waitcnt vmcnt(0)");
    __syncthreads();

    short8v a_frag[4], b_frag[4];
    #pragma unroll
    for(int i=0;i<4;i++){
      int row = wm + i*16 + r16;
      a_frag[i] = *reinterpret_cast<const short8v*>(As + row*32 + ((kg ^ (row&3))<<3));
    }
    #pragma unroll
    for(int j=0;j<4;j++){
      int row = wn + j*16 + r16;
      b_frag[j] = *reinterpret_cast<const short8v*>(Bs + row*32 + ((kg ^ (row&3))<<3));
    }
    #pragma unroll
    for(int i=0;i<4;i++)
      #pragma unroll
      for(int j=0;j<4;j++)
        acc[i][j] = __builtin_amdgcn_mfma_f32_16x16x32_bf16(a_frag[i], b_frag[j], acc[i][j], 0, 0, 0);
    __syncthreads();
  }

  // C/D layout: col = lane&15, row = (lane>>4)*4 + reg
  #pragma unroll
  for(int i=0;i<4;i++){
    #pragma unroll
    for(int j=0;j<4;j++){
      #pragma unroll
      for(int r=0;r<4;r++){
        int row = bm + wm + i*16 + kg*4 + r;
        int col = bn + wn + j*16 + r16;
        if(row < M) Cb[(size_t)row*512 + col] = f2b(acc[i][j][r]);
      }
    }
  }
}

// ---------- layer-3 MFMA GEMM: h3b[M,40] bf16 = A[M,512] @ W3; B resident in LDS ----------
__global__ __launch_bounds__(256) void k_gemm3m(const ushortT* __restrict__ A,
                                                const ushortT* __restrict__ Wt3p,
                                                ushortT* __restrict__ Cb, int M){
  const int K = 512;
  __shared__ __align__(16) ushortT As[128*32];      // 8 KB
  __shared__ __align__(16) ushortT Bs[64*48*8];     // 48 KB, [kslot][n][8]
  int bm = blockIdx.x*128;
  int tid = threadIdx.x, wave = tid>>6, lane = tid&63;

  // stage entire packed B once
  #pragma unroll
  for(int it=0; it<12; it++){
    int o = (it*256 + tid)*8;
    *reinterpret_cast<u16x8*>(Bs + o) = *reinterpret_cast<const u16x8*>(Wt3p + o);
  }

  int l4 = lane>>2, s4 = lane&3;
  int src_slot = s4 ^ (l4 & 3);
  int r16 = lane&15, kg = lane>>4;
  f32x4 acc[2][3] = {};

  for(int k0=0;k0<K;k0+=32){
    #pragma unroll
    for(int c=0;c<2;c++){
      int chunk = wave*2 + c;
      int arow = bm + chunk*16 + l4; if(arow > M-1) arow = M-1;
      const ushortT* ga = A + (size_t)arow*K + k0 + src_slot*8;
      __builtin_amdgcn_global_load_lds(
          (const __attribute__((address_space(1))) void*)ga,
          (__attribute__((address_space(3))) void*)(As + chunk*16*32), 16, 0, 0);
    }
    asm volatile("s_waitcnt vmcnt(0)");
    __syncthreads();

    short8v a_frag[2], b_frag[3];
    #pragma unroll
    for(int i=0;i<2;i++){
      int row = wave*32 + i*16 + r16;
      a_frag[i] = *reinterpret_cast<const short8v*>(As + row*32 + ((kg ^ (row&3))<<3));
    }
    int kslot = (k0>>3) + kg;
    #pragma unroll
    for(int j=0;j<3;j++){
      b_frag[j] = *reinterpret_cast<const short8v*>(Bs + kslot*384 + (j*16 + r16)*8);
    }
    #pragma unroll
    for(int i=0;i<2;i++)
      #pragma unroll
      for(int j=0;j<3;j++)
        acc[i][j] = __builtin_amdgcn_mfma_f32_16x16x32_bf16(a_frag[i], b_frag[j], acc[i][j], 0, 0, 0);
    __syncthreads();
  }

  #pragma unroll
  for(int i=0;i<2;i++){
    #pragma unroll
    for(int j=0;j<3;j++){
      #pragma unroll
      for(int r=0;r<4;r++){
        int row = bm + wave*32 + i*16 + kg*4 + r;
        int col = j*16 + r16;
        if(row < M && col < 40) Cb[(size_t)row*40 + col] = f2b(acc[i][j][r]);
      }
    }
  }
}

// ---------- per-node attention coefficients, H=8 C=64 (bf16 features) ----------
__global__ void k_attn8(const ushortT* __restrict__ feat, const float* __restrict__ atts,
                        const float* __restrict__ attd, float* __restrict__ a_s,
                        float* __restrict__ a_d){
  int n = blockIdx.x*4 + (threadIdx.x>>6);
  int lane = threadIdx.x & 63;
  if(n >= NN) return;
  int c0 = lane*8;
  u16x8 v = *reinterpret_cast<const u16x8*>(feat + (size_t)n*512 + c0);
  float s1 = 0.f, s2 = 0.f;
  #pragma unroll
  for(int j=0;j<8;j++){
    float f = b2f((ushortT)v[j]);
    s1 += f*atts[c0+j];
    s2 += f*attd[c0+j];
  }
  #pragma unroll
  for(int off=1; off<8; off<<=1){
    s1 += __shfl_xor(s1, off);
    s2 += __shfl_xor(s2, off);
  }
  if((lane&7) == 0){
    int head = lane>>3;
    a_s[n*8+head] = s1;
    a_d[n*8+head] = s2;
  }
}

// bf16 features, H=1 C=40 (layer 3)
__global__ void k_attn1b(const ushortT* __restrict__ feat, const float* __restrict__ atts,
                         const float* __restrict__ attd, float* __restrict__ a_s,
                         float* __restrict__ a_d){
  int n = blockIdx.x*4 + (threadIdx.x>>6);
  int lane = threadIdx.x & 63;
  if(n >= NN) return;
  float s1 = 0.f, s2 = 0.f;
  if(lane < 40){
    float v = b2f(feat[(size_t)n*40 + lane]);
    s1 = v*atts[lane];
    s2 = v*attd[lane];
  }
  for(int off=32; off; off>>=1){
    s1 += __shfl_xor(s1, off);
    s2 += __shfl_xor(s2, off);
  }
  if(lane == 0){ a_s[n] = s1; a_d[n] = s2; }
}

// ---------- edge precompute: per CSR pos, all 8 heads' alpha ----------
// packed u32 record: (src << 16) | bf16(alpha). 8 sliced planes so each XCD
// later streams only its plane. src < 2^15; alpha > 0 fits bf16.
__global__ void k_edge_pre(const int* __restrict__ srcs, const int* __restrict__ edsts,
                           const float* __restrict__ a_s, const float* __restrict__ a_d,
                           unsigned* __restrict__ rec){
  int pos = blockIdx.x*blockDim.x + threadIdx.x;
  if(pos >= ETOT) return;
  int s = srcs[pos], d = edsts[pos];
  float4 s0 = *reinterpret_cast<const float4*>(a_s + ((size_t)s<<3));
  float4 s1 = *reinterpret_cast<const float4*>(a_s + ((size_t)s<<3) + 4);
  float4 d0 = *reinterpret_cast<const float4*>(a_d + ((size_t)d<<3));
  float4 d1 = *reinterpret_cast<const float4*>(a_d + ((size_t)d<<3) + 4);
  float l[8] = { s0.x+d0.x, s0.y+d0.y, s0.z+d0.z, s0.w+d0.w,
                 s1.x+d1.x, s1.y+d1.y, s1.z+d1.z, s1.w+d1.w };
  unsigned sh = ((unsigned)s) << 16;
  #pragma unroll
  for(int h=0;h<8;h++){
    float al = __expf(fmaxf(l[h], NEG*l[h]));
    rec[(size_t)h*ETOT + pos] = sh | (unsigned)f2b(al);
  }
}

// ---------- fused CSR aggregate (H=8,C=64), sliced + dst-per-lane-group ----------
// Block b: slice = b&7 (XCD via round-robin), 8 waves x 8 dsts = 64 dsts/block.
// Lane = ds*8+cg: lane exclusively owns (dst ds, 8 channels) -> NO shuffle epilogue.
// 4-deep pipeline: 4 packed-record broadcasts + 4 feat gathers in flight.
__global__ __launch_bounds__(512) void k_agg512(const ushortT* __restrict__ feat,
    const unsigned* __restrict__ rec, const int* __restrict__ rowstart,
    const float* __restrict__ bias, ushortT* __restrict__ outb){
  int slice = blockIdx.x & 7;
  int lane  = threadIdx.x & 63;
  int ds = lane>>3, cg = lane&7;
  int d = (blockIdx.x>>3)*64 + (int)(threadIdx.x>>6)*8 + ds;
  bool dok = d < NN;
  int p  = dok ? rowstart[d]   : 0;
  int p1 = dok ? rowstart[d+1] : 0;
  const unsigned* plane = rec + (size_t)slice*ETOT;
  unsigned cbase = ((unsigned)slice<<6) + ((unsigned)cg<<3);
  float acc[8] = {0.f,0.f,0.f,0.f,0.f,0.f,0.f,0.f};
  float dsum = 0.f;

  for(; p+4 <= p1; p += 4){
    unsigned r0 = plane[p];
    unsigned r1 = plane[p+1];
    unsigned r2 = plane[p+2];
    unsigned r3 = plane[p+3];
    u16x8 v0 = *reinterpret_cast<const u16x8*>(feat + ((r0>>16<<9) + cbase));
    u16x8 v1 = *reinterpret_cast<const u16x8*>(feat + ((r1>>16<<9) + cbase));
    u16x8 v2 = *reinterpret_cast<const u16x8*>(feat + ((r2>>16<<9) + cbase));
    u16x8 v3 = *reinterpret_cast<const u16x8*>(feat + ((r3>>16<<9) + cbase));
    float al0 = b2f((ushortT)(r0 & 0xffffu));
    float al1 = b2f((ushortT)(r1 & 0xffffu));
    float al2 = b2f((ushortT)(r2 & 0xffffu));
    float al3 = b2f((ushortT)(r3 & 0xffffu));
    dsum += al0 + al1 + al2 + al3;
    #pragma unroll
    for(int j=0;j<8;j++) acc[j] += al0*b2f((ushortT)v0[j]);
    #pragma unroll
    for(int j=0;j<8;j++) acc[j] += al1*b2f((ushortT)v1[j]);
    #pragma unroll
    for(int j=0;j<8;j++) acc[j] += al2*b2f((ushortT)v2[j]);
    #pragma unroll
    for(int j=0;j<8;j++) acc[j] += al3*b2f((ushortT)v3[j]);
  }
  // predicated tail (<=3 per dst)
  while(__any(p < p1)){
    bool valid = p < p1;
    int pc = valid ? p : 0;
    unsigned r = plane[pc];
    float al = valid ? b2f((ushortT)(r & 0xffffu)) : 0.f;
    u16x8 v = *reinterpret_cast<const u16x8*>(feat + ((r>>16<<9) + cbase));
    dsum += al;
    #pragma unroll
    for(int j=0;j<8;j++) acc[j] += al*b2f((ushortT)v[j]);
    p++;
  }

  if(dok){
    float invd = 1.f/(dsum + 1e-16f);
    u16x8 ov;
    #pragma unroll
    for(int j=0;j<8;j++){
      float o = acc[j]*invd + bias[cbase+j];
      o = (o > 0.f) ? o : (__expf(o) - 1.f);
      ov[j] = f2b(o);
    }
    *reinterpret_cast<u16x8*>(outb + (size_t)d*512 + cbase) = ov;
  }
}

// ---------- layer-3 aggregate (H=1,C=40, bf16 feat) + bias + log_softmax ----------
__global__ void k_agg_l3(const ushortT* __restrict__ feat,
    const float* __restrict__ a_s, const float* __restrict__ a_d,
    const int* __restrict__ rowstart, const int* __restrict__ srcs,
    const float* __restrict__ bias, float* __restrict__ outp){
  int d = blockIdx.x;
  int lane = threadIdx.x;       // 64 threads
  bool act = lane < 40;
  int li = act ? lane : 0;
  float ad_v = a_d[d];
  float acc = 0.f, dsum = 0.f;
  int p0 = rowstart[d], p1 = rowstart[d+1];
  int p = p0;
  for(; p+4 <= p1; p += 4){
    int s0_ = srcs[p], s1_ = srcs[p+1], s2_ = srcs[p+2], s3_ = srcs[p+3];
    float l0 = a_s[s0_] + ad_v, l1 = a_s[s1_] + ad_v;
    float l2 = a_s[s2_] + ad_v, l3 = a_s[s3_] + ad_v;
    float v0 = b2f(feat[(size_t)s0_*40 + li]);
    float v1 = b2f(feat[(size_t)s1_*40 + li]);
    float v2 = b2f(feat[(size_t)s2_*40 + li]);
    float v3 = b2f(feat[(size_t)s3_*40 + li]);
    float al0 = __expf(fmaxf(l0, NEG*l0));
    float al1 = __expf(fmaxf(l1, NEG*l1));
    float al2 = __expf(fmaxf(l2, NEG*l2));
    float al3 = __expf(fmaxf(l3, NEG*l3));
    dsum += al0 + al1 + al2 + al3;
    acc += al0*v0 + al1*v1 + al2*v2 + al3*v3;
  }
  for(; p<p1; p++){
    int s_ = srcs[p];
    float l = a_s[s_] + ad_v;
    float al = __expf(fmaxf(l, NEG*l));
    dsum += al;
    acc += al*b2f(feat[(size_t)s_*40 + li]);
  }
  float invd = 1.f/(dsum + 1e-16f);
  float o = act ? (acc*invd + bias[lane]) : -1e30f;
  float m = o;
  for(int off=32; off; off>>=1) m = fmaxf(m, __shfl_xor(m, off));
  float e_ = act ? expf(o - m) : 0.f;
  float ssum = e_;
  for(int off=32; off; off>>=1) ssum += __shfl_xor(ssum, off);
  if(act) outp[(size_t)d*40 + lane] = o - m - logf(ssum);
}

extern "C" void kernel_launch(void* const* d_in, const int* in_sizes, int n_in,
                              void* d_out, int out_size, void* d_ws, size_t ws_size,
                              hipStream_t stream){
  const float* x   = (const float*)d_in[0];
  const int*   ei  = (const int*)d_in[1];
  const int*   esrc = ei;
  const int*   edst = ei + EE;
  const float* W1  = (const float*)d_in[2];
  const float* as1 = (const float*)d_in[3];
  const float* ad1 = (const float*)d_in[4];
  const float* b1  = (const float*)d_in[5];
  const float* W2  = (const float*)d_in[6];
  const float* as2 = (const float*)d_in[7];
  const float* ad2 = (const float*)d_in[8];
  const float* b2  = (const float*)d_in[9];
  const float* W3  = (const float*)d_in[10];
  const float* as3 = (const float*)d_in[11];
  const float* ad3 = (const float*)d_in[12];
  const float* b3  = (const float*)d_in[13];
  float* out = (float*)d_out;

  char* w = (char*)d_ws;
  size_t off = 0;
  auto alloc = [&](size_t bytes)->char*{
    char* p = w + off;
    off = (off + bytes + 255) & ~(size_t)255;
    return p;
  };
  ushortT*  xb   = (ushortT*)alloc((size_t)NN*512*2);
  ushortT*  fA   = (ushortT*)alloc((size_t)NN*512*2);
  ushortT*  fB   = (ushortT*)alloc((size_t)NN*512*2);
  ushortT*  h3b  = (ushortT*)alloc((size_t)NN*40*2);
  ushortT*  Wt1  = (ushortT*)alloc((size_t)512*512*2);
  ushortT*  Wt2  = (ushortT*)alloc((size_t)512*512*2);
  ushortT*  Wt3p = (ushortT*)alloc((size_t)64*48*8*2);
  float*    a_s  = (float*)alloc((size_t)NN*8*4);
  float*    a_d  = (float*)alloc((size_t)NN*8*4);
  unsigned* rec  = (unsigned*)alloc((size_t)8*ETOT*4);
  int* rowstart  = (int*)alloc((size_t)(NN+1)*4);
  int* cursor    = (int*)alloc((size_t)NN*4);
  int* counts    = (int*)alloc((size_t)NN*4);
  int* srcs      = (int*)alloc((size_t)ETOT*4);
  int* edsts     = (int*)alloc((size_t)ETOT*4);

  // ---- conversions (independent of CSR) ----
  k_cvt<<<(NN*512/4 + 255)/256, 256, 0, stream>>>(x, xb, NN*512/4);
  dim3 wt_grid(16, 16);
  k_wtrans<<<wt_grid, 256, 0, stream>>>(W1, Wt1);
  k_wtrans<<<wt_grid, 256, 0, stream>>>(W2, Wt2);
  k_wtrans3<<<(64*48*8 + 255)/256, 256, 0, stream>>>(W3, Wt3p);

  // ---- CSR build (dst-grouped) ----
  hipMemsetAsync(counts, 0, (size_t)NN*4, stream);
  hipMemsetAsync(cursor, 0, (size_t)NN*4, stream);
  k_count<<<(ETOT+255)/256, 256, 0, stream>>>(edst, counts);
  k_scan<<<1, 1024, 0, stream>>>(counts, rowstart);
  k_fill<<<(ETOT+255)/256, 256, 0, stream>>>(esrc, edst, rowstart, cursor, srcs, edsts);

  dim3 mgrid((NN+127)/128, 4);
  int edge_blocks = (ETOT + 255)/256;
  int agg_blocks  = ((NN + 63)/64)*8;

  // ---- layer 1 ----
  k_gemm_bf16<<<mgrid, 256, 0, stream>>>(xb, Wt1, fA, NN);
  k_attn8<<<(NN+3)/4, 256, 0, stream>>>(fA, as1, ad1, a_s, a_d);
  k_edge_pre<<<edge_blocks, 256, 0, stream>>>(srcs, edsts, a_s, a_d, rec);
  k_agg512<<<agg_blocks, 512, 0, stream>>>(fA, rec, rowstart, b1, fB);

  // ---- layer 2 ----
  k_gemm_bf16<<<mgrid, 256, 0, stream>>>(fB, Wt2, fA, NN);
  k_attn8<<<(NN+3)/4, 256, 0, stream>>>(fA, as2, ad2, a_s, a_d);
  k_edge_pre<<<edge_blocks, 256, 0, stream>>>(srcs, edsts, a_s, a_d, rec);
  k_agg512<<<agg_blocks, 512, 0, stream>>>(fA, rec, rowstart, b2, fB);

  // ---- layer 3 ----
  k_gemm3m<<<(NN+127)/128, 256, 0, stream>>>(fB, Wt3p, h3b, NN);
  k_attn1b<<<(NN+3)/4, 256, 0, stream>>>(h3b, as3, ad3, a_s, a_d);
  k_agg_l3<<<NN, 64, 0, stream>>>(h3b, a_s, a_d, rowstart, srcs, b3, out);
}

// Round 15
// 233.351 us; speedup vs baseline: 1.6052x; 1.0291x over previous
//
#include <hip/hip_runtime.h>
#include <math.h>

#define NN 20000
#define EE 320000
#define ETOT (EE + NN)
#define NEG 0.2f

typedef unsigned short ushortT;
typedef __attribute__((ext_vector_type(8))) short short8v;       // 8 bf16 (4 VGPRs)
typedef __attribute__((ext_vector_type(8))) unsigned short u16x8;
typedef __attribute__((ext_vector_type(4))) float f32x4;

// ---------- helpers ----------
__device__ __forceinline__ ushortT f2b(float f){            // fp32 -> bf16 (RNE)
  unsigned u = __float_as_uint(f);
  u += 0x7FFFu + ((u >> 16) & 1u);
  return (ushortT)(u >> 16);
}
__device__ __forceinline__ float b2f(ushortT b){
  return __uint_as_float(((unsigned)b) << 16);
}

// ---------- fused prep: x->bf16 | W1^T | W2^T | W3 pack ----------
// blocks [0,10000): cvt; [10000,10256): W1; [10256,10512): W2; [10512,10608): W3
__global__ void k_prep(const float* __restrict__ x, ushortT* __restrict__ xb,
                       const float* __restrict__ W1, ushortT* __restrict__ Wt1,
                       const float* __restrict__ W2, ushortT* __restrict__ Wt2,
                       const float* __restrict__ W3, ushortT* __restrict__ Wt3p){
  int b = blockIdx.x;
  if(b < 10000){
    int i = b*256 + threadIdx.x;          // i < 2.56M, 4 elems each
    float4 v = *reinterpret_cast<const float4*>(x + (size_t)i*4);
    ushort4 o;
    o.x = f2b(v.x); o.y = f2b(v.y); o.z = f2b(v.z); o.w = f2b(v.w);
    *reinterpret_cast<ushort4*>(xb + (size_t)i*4) = o;
  } else if(b < 10512){
    const float* W = (b < 10256) ? W1 : W2;
    ushortT* Wt    = (b < 10256) ? Wt1 : Wt2;
    int bb = (b < 10256) ? (b - 10000) : (b - 10256);
    __shared__ float t[32][33];
    int bk = (bb & 15)*32, bn = (bb >> 4)*32;
    int tx = threadIdx.x & 31, ty = threadIdx.x >> 5;
    for(int r=0;r<32;r+=8)
      t[ty+r][tx] = W[(size_t)(bk+ty+r)*512 + bn+tx];
    __syncthreads();
    for(int r=0;r<32;r+=8)
      Wt[(size_t)(bn+ty+r)*512 + bk+tx] = f2b(t[tx][ty+r]);
  } else {
    int idx = (b - 10512)*256 + threadIdx.x;
    if(idx < 64*48*8){
      int kslot = idx / 384;
      int rem = idx - kslot*384;
      int n = rem >> 3;
      int jj = rem & 7;
      int k = kslot*8 + jj;
      float v = (n < 40) ? W3[(size_t)k*40 + n] : 0.f;
      Wt3p[idx] = f2b(v);
    }
  }
}

// ---------- CSR build ----------
__global__ void k_count(const int* __restrict__ edst, int* __restrict__ counts){
  int e = blockIdx.x*blockDim.x + threadIdx.x;
  if(e < ETOT){
    int d = (e < EE) ? edst[e] : (e - EE);
    atomicAdd(&counts[d], 1);
  }
}

__global__ void k_scan(const int* __restrict__ counts, int* __restrict__ rowstart){
  __shared__ int lds[1024];
  int tid = threadIdx.x;
  int base = tid*20;
  int s = 0;
  for(int j=0;j<20;j++){ int i=base+j; if(i<NN) s += counts[i]; }
  lds[tid] = s; __syncthreads();
  for(int off=1; off<1024; off<<=1){
    int v = (tid>=off) ? lds[tid-off] : 0;
    __syncthreads();
    lds[tid] += v;
    __syncthreads();
  }
  int run = lds[tid] - s;
  for(int j=0;j<20;j++){
    int i = base+j;
    if(i <= NN){
      rowstart[i] = run;
      if(i < NN) run += counts[i];
    }
  }
}

__global__ void k_fill(const int* __restrict__ esrc, const int* __restrict__ edst,
                       const int* __restrict__ rowstart,
                       int* __restrict__ cursor, int* __restrict__ srcs,
                       int* __restrict__ edsts){
  int e = blockIdx.x*blockDim.x + threadIdx.x;
  if(e < ETOT){
    int d = (e < EE) ? edst[e] : (e - EE);
    int s = (e < EE) ? esrc[e] : (e - EE);
    int pos = rowstart[d] + atomicAdd(&cursor[d], 1);
    srcs[pos] = s;
    edsts[pos] = d;
  }
}

// ---------- bf16 MFMA GEMM, BK=64: C[M,512] = A[M,512] @ Bt[512,512]^T ----------
// 128x128 tile, 8 K-steps of 64 (half the barriers of BK=32), 8-slot XOR swizzle
// (2-way LDS conflict, free). Staging: chunk = 8 rows x 128B; lane l8=row, s8=slot;
// source fetches logical slot s8^l8 so linear LDS + swizzled read is consistent.
__global__ __launch_bounds__(256) void k_gemm_bf16(
    const ushortT* __restrict__ A, const ushortT* __restrict__ Bt,
    ushortT* __restrict__ Cb, int M)
{
  const int K = 512;
  __shared__ __align__(16) ushortT As[128*64];   // 16 KB
  __shared__ __align__(16) ushortT Bs[128*64];   // 16 KB
  int bm = blockIdx.x*128, bn = blockIdx.y*128;
  int tid = threadIdx.x, wave = tid>>6, lane = tid&63;
  int wm = (wave>>1)*64, wn = (wave&1)*64;
  f32x4 acc[4][4] = {};

  int l8 = lane>>3;                 // row within 8-row staging chunk
  int s8 = lane&7;                  // phys 16-B slot within 128-B row
  int src_slot = s8 ^ l8;           // logical slot fetched into phys s8 (row&7==l8)
  int r16 = lane&15, kg = lane>>4;

  for(int k0=0;k0<K;k0+=64){
    #pragma unroll
    for(int c=0;c<4;c++){
      int chunk = wave*4 + c;                       // 16 chunks x 8 rows
      int arow = bm + chunk*8 + l8; if(arow > M-1) arow = M-1;
      const ushortT* ga = A + (size_t)arow*K + k0 + src_slot*8;
      __builtin_amdgcn_global_load_lds(
          (const __attribute__((address_space(1))) void*)ga,
          (__attribute__((address_space(3))) void*)(As + chunk*8*64), 16, 0, 0);
      int brow = bn + chunk*8 + l8;
      const ushortT* gb = Bt + (size_t)brow*K + k0 + src_slot*8;
      __builtin_amdgcn_global_load_lds(
          (const __attribute__((address_space(1))) void*)gb,
          (__attribute__((address_space(3))) void*)(Bs + chunk*8*64), 16, 0, 0);
    }
    asm volatile("s_waitcnt vmcnt(0)");
    __syncthreads();

    #pragma unroll
    for(int h=0;h<2;h++){
      short8v a_frag[4], b_frag[4];
      #pragma unroll
      for(int i=0;i<4;i++){
        int row = wm + i*16 + r16;
        a_frag[i] = *reinterpret_cast<const short8v*>(As + row*64 + (((h*4+kg) ^ (row&7))<<3));
      }
      #pragma unroll
      for(int j=0;j<4;j++){
        int row = wn + j*16 + r16;
        b_frag[j] = *reinterpret_cast<const short8v*>(Bs + row*64 + (((h*4+kg) ^ (row&7))<<3));
      }
      #pragma unroll
      for(int i=0;i<4;i++)
        #pragma unroll
        for(int j=0;j<4;j++)
          acc[i][j] = __builtin_amdgcn_mfma_f32_16x16x32_bf16(a_frag[i], b_frag[j], acc[i][j], 0, 0, 0);
    }
    __syncthreads();
  }

  // C/D layout: col = lane&15, row = (lane>>4)*4 + reg
  #pragma unroll
  for(int i=0;i<4;i++){
    #pragma unroll
    for(int j=0;j<4;j++){
      #pragma unroll
      for(int r=0;r<4;r++){
        int row = bm + wm + i*16 + kg*4 + r;
        int col = bn + wn + j*16 + r16;
        if(row < M) Cb[(size_t)row*512 + col] = f2b(acc[i][j][r]);
      }
    }
  }
}

// ---------- layer-3 MFMA GEMM: h3b[M,40] bf16 = A[M,512] @ W3; B resident in LDS ----------
__global__ __launch_bounds__(256) void k_gemm3m(const ushortT* __restrict__ A,
                                                const ushortT* __restrict__ Wt3p,
                                                ushortT* __restrict__ Cb, int M){
  const int K = 512;
  __shared__ __align__(16) ushortT As[128*32];      // 8 KB
  __shared__ __align__(16) ushortT Bs[64*48*8];     // 48 KB, [kslot][n][8]
  int bm = blockIdx.x*128;
  int tid = threadIdx.x, wave = tid>>6, lane = tid&63;

  // stage entire packed B once
  #pragma unroll
  for(int it=0; it<12; it++){
    int o = (it*256 + tid)*8;
    *reinterpret_cast<u16x8*>(Bs + o) = *reinterpret_cast<const u16x8*>(Wt3p + o);
  }

  int l4 = lane>>2, s4 = lane&3;
  int src_slot = s4 ^ (l4 & 3);
  int r16 = lane&15, kg = lane>>4;
  f32x4 acc[2][3] = {};

  for(int k0=0;k0<K;k0+=32){
    #pragma unroll
    for(int c=0;c<2;c++){
      int chunk = wave*2 + c;
      int arow = bm + chunk*16 + l4; if(arow > M-1) arow = M-1;
      const ushortT* ga = A + (size_t)arow*K + k0 + src_slot*8;
      __builtin_amdgcn_global_load_lds(
          (const __attribute__((address_space(1))) void*)ga,
          (__attribute__((address_space(3))) void*)(As + chunk*16*32), 16, 0, 0);
    }
    asm volatile("s_waitcnt vmcnt(0)");
    __syncthreads();

    short8v a_frag[2], b_frag[3];
    #pragma unroll
    for(int i=0;i<2;i++){
      int row = wave*32 + i*16 + r16;
      a_frag[i] = *reinterpret_cast<const short8v*>(As + row*32 + ((kg ^ (row&3))<<3));
    }
    int kslot = (k0>>3) + kg;
    #pragma unroll
    for(int j=0;j<3;j++){
      b_frag[j] = *reinterpret_cast<const short8v*>(Bs + kslot*384 + (j*16 + r16)*8);
    }
    #pragma unroll
    for(int i=0;i<2;i++)
      #pragma unroll
      for(int j=0;j<3;j++)
        acc[i][j] = __builtin_amdgcn_mfma_f32_16x16x32_bf16(a_frag[i], b_frag[j], acc[i][j], 0, 0, 0);
    __syncthreads();
  }

  #pragma unroll
  for(int i=0;i<2;i++){
    #pragma unroll
    for(int j=0;j<3;j++){
      #pragma unroll
      for(int r=0;r<4;r++){
        int row = bm + wave*32 + i*16 + kg*4 + r;
        int col = j*16 + r16;
        if(row < M && col < 40) Cb[(size_t)row*40 + col] = f2b(acc[i][j][r]);
      }
    }
  }
}

// ---------- per-node attention coefficients, H=8 C=64 (bf16 features) ----------
__global__ void k_attn8(const ushortT* __restrict__ feat, const float* __restrict__ atts,
                        const float* __restrict__ attd, float* __restrict__ a_s,
                        float* __restrict__ a_d){
  int n = blockIdx.x*4 + (threadIdx.x>>6);
  int lane = threadIdx.x & 63;
  if(n >= NN) return;
  int c0 = lane*8;
  u16x8 v = *reinterpret_cast<const u16x8*>(feat + (size_t)n*512 + c0);
  float s1 = 0.f, s2 = 0.f;
  #pragma unroll
  for(int j=0;j<8;j++){
    float f = b2f((ushortT)v[j]);
    s1 += f*atts[c0+j];
    s2 += f*attd[c0+j];
  }
  #pragma unroll
  for(int off=1; off<8; off<<=1){
    s1 += __shfl_xor(s1, off);
    s2 += __shfl_xor(s2, off);
  }
  if((lane&7) == 0){
    int head = lane>>3;
    a_s[n*8+head] = s1;
    a_d[n*8+head] = s2;
  }
}

// bf16 features, H=1 C=40 (layer 3)
__global__ void k_attn1b(const ushortT* __restrict__ feat, const float* __restrict__ atts,
                         const float* __restrict__ attd, float* __restrict__ a_s,
                         float* __restrict__ a_d){
  int n = blockIdx.x*4 + (threadIdx.x>>6);
  int lane = threadIdx.x & 63;
  if(n >= NN) return;
  float s1 = 0.f, s2 = 0.f;
  if(lane < 40){
    float v = b2f(feat[(size_t)n*40 + lane]);
    s1 = v*atts[lane];
    s2 = v*attd[lane];
  }
  for(int off=32; off; off>>=1){
    s1 += __shfl_xor(s1, off);
    s2 += __shfl_xor(s2, off);
  }
  if(lane == 0){ a_s[n] = s1; a_d[n] = s2; }
}

// ---------- edge precompute: per CSR pos, all 8 heads' alpha ----------
// packed u32 record: (src << 16) | bf16(alpha). 8 sliced planes so each XCD
// later streams only its plane. src < 2^15; alpha > 0 fits bf16.
__global__ void k_edge_pre(const int* __restrict__ srcs, const int* __restrict__ edsts,
                           const float* __restrict__ a_s, const float* __restrict__ a_d,
                           unsigned* __restrict__ rec){
  int pos = blockIdx.x*blockDim.x + threadIdx.x;
  if(pos >= ETOT) return;
  int s = srcs[pos], d = edsts[pos];
  float4 s0 = *reinterpret_cast<const float4*>(a_s + ((size_t)s<<3));
  float4 s1 = *reinterpret_cast<const float4*>(a_s + ((size_t)s<<3) + 4);
  float4 d0 = *reinterpret_cast<const float4*>(a_d + ((size_t)d<<3));
  float4 d1 = *reinterpret_cast<const float4*>(a_d + ((size_t)d<<3) + 4);
  float l[8] = { s0.x+d0.x, s0.y+d0.y, s0.z+d0.z, s0.w+d0.w,
                 s1.x+d1.x, s1.y+d1.y, s1.z+d1.z, s1.w+d1.w };
  unsigned sh = ((unsigned)s) << 16;
  #pragma unroll
  for(int h=0;h<8;h++){
    float al = __expf(fmaxf(l[h], NEG*l[h]));
    rec[(size_t)h*ETOT + pos] = sh | (unsigned)f2b(al);
  }
}

// ---------- fused CSR aggregate (H=8,C=64), sliced + dst-per-lane-group ----------
__global__ __launch_bounds__(512) void k_agg512(const ushortT* __restrict__ feat,
    const unsigned* __restrict__ rec, const int* __restrict__ rowstart,
    const float* __restrict__ bias, ushortT* __restrict__ outb){
  int slice = blockIdx.x & 7;
  int lane  = threadIdx.x & 63;
  int ds = lane>>3, cg = lane&7;
  int d = (blockIdx.x>>3)*64 + (int)(threadIdx.x>>6)*8 + ds;
  bool dok = d < NN;
  int p  = dok ? rowstart[d]   : 0;
  int p1 = dok ? rowstart[d+1] : 0;
  const unsigned* plane = rec + (size_t)slice*ETOT;
  unsigned cbase = ((unsigned)slice<<6) + ((unsigned)cg<<3);
  float acc[8] = {0.f,0.f,0.f,0.f,0.f,0.f,0.f,0.f};
  float dsum = 0.f;

  for(; p+4 <= p1; p += 4){
    unsigned r0 = plane[p];
    unsigned r1 = plane[p+1];
    unsigned r2 = plane[p+2];
    unsigned r3 = plane[p+3];
    u16x8 v0 = *reinterpret_cast<const u16x8*>(feat + ((r0>>16<<9) + cbase));
    u16x8 v1 = *reinterpret_cast<const u16x8*>(feat + ((r1>>16<<9) + cbase));
    u16x8 v2 = *reinterpret_cast<const u16x8*>(feat + ((r2>>16<<9) + cbase));
    u16x8 v3 = *reinterpret_cast<const u16x8*>(feat + ((r3>>16<<9) + cbase));
    float al0 = b2f((ushortT)(r0 & 0xffffu));
    float al1 = b2f((ushortT)(r1 & 0xffffu));
    float al2 = b2f((ushortT)(r2 & 0xffffu));
    float al3 = b2f((ushortT)(r3 & 0xffffu));
    dsum += al0 + al1 + al2 + al3;
    #pragma unroll
    for(int j=0;j<8;j++) acc[j] += al0*b2f((ushortT)v0[j]);
    #pragma unroll
    for(int j=0;j<8;j++) acc[j] += al1*b2f((ushortT)v1[j]);
    #pragma unroll
    for(int j=0;j<8;j++) acc[j] += al2*b2f((ushortT)v2[j]);
    #pragma unroll
    for(int j=0;j<8;j++) acc[j] += al3*b2f((ushortT)v3[j]);
  }
  // predicated tail (<=3 per dst)
  while(__any(p < p1)){
    bool valid = p < p1;
    int pc = valid ? p : 0;
    unsigned r = plane[pc];
    float al = valid ? b2f((ushortT)(r & 0xffffu)) : 0.f;
    u16x8 v = *reinterpret_cast<const u16x8*>(feat + ((r>>16<<9) + cbase));
    dsum += al;
    #pragma unroll
    for(int j=0;j<8;j++) acc[j] += al*b2f((ushortT)v[j]);
    p++;
  }

  if(dok){
    float invd = 1.f/(dsum + 1e-16f);
    u16x8 ov;
    #pragma unroll
    for(int j=0;j<8;j++){
      float o = acc[j]*invd + bias[cbase+j];
      o = (o > 0.f) ? o : (__expf(o) - 1.f);
      ov[j] = f2b(o);
    }
    *reinterpret_cast<u16x8*>(outb + (size_t)d*512 + cbase) = ov;
  }
}

// ---------- layer-3 aggregate (H=1,C=40, bf16 feat) + bias + log_softmax ----------
__global__ void k_agg_l3(const ushortT* __restrict__ feat,
    const float* __restrict__ a_s, const float* __restrict__ a_d,
    const int* __restrict__ rowstart, const int* __restrict__ srcs,
    const float* __restrict__ bias, float* __restrict__ outp){
  int d = blockIdx.x;
  int lane = threadIdx.x;       // 64 threads
  bool act = lane < 40;
  int li = act ? lane : 0;
  float ad_v = a_d[d];
  float acc = 0.f, dsum = 0.f;
  int p0 = rowstart[d], p1 = rowstart[d+1];
  int p = p0;
  for(; p+4 <= p1; p += 4){
    int s0_ = srcs[p], s1_ = srcs[p+1], s2_ = srcs[p+2], s3_ = srcs[p+3];
    float l0 = a_s[s0_] + ad_v, l1 = a_s[s1_] + ad_v;
    float l2 = a_s[s2_] + ad_v, l3 = a_s[s3_] + ad_v;
    float v0 = b2f(feat[(size_t)s0_*40 + li]);
    float v1 = b2f(feat[(size_t)s1_*40 + li]);
    float v2 = b2f(feat[(size_t)s2_*40 + li]);
    float v3 = b2f(feat[(size_t)s3_*40 + li]);
    float al0 = __expf(fmaxf(l0, NEG*l0));
    float al1 = __expf(fmaxf(l1, NEG*l1));
    float al2 = __expf(fmaxf(l2, NEG*l2));
    float al3 = __expf(fmaxf(l3, NEG*l3));
    dsum += al0 + al1 + al2 + al3;
    acc += al0*v0 + al1*v1 + al2*v2 + al3*v3;
  }
  for(; p<p1; p++){
    int s_ = srcs[p];
    float l = a_s[s_] + ad_v;
    float al = __expf(fmaxf(l, NEG*l));
    dsum += al;
    acc += al*b2f(feat[(size_t)s_*40 + li]);
  }
  float invd = 1.f/(dsum + 1e-16f);
  float o = act ? (acc*invd + bias[lane]) : -1e30f;
  float m = o;
  for(int off=32; off; off>>=1) m = fmaxf(m, __shfl_xor(m, off));
  float e_ = act ? expf(o - m) : 0.f;
  float ssum = e_;
  for(int off=32; off; off>>=1) ssum += __shfl_xor(ssum, off);
  if(act) outp[(size_t)d*40 + lane] = o - m - logf(ssum);
}

extern "C" void kernel_launch(void* const* d_in, const int* in_sizes, int n_in,
                              void* d_out, int out_size, void* d_ws, size_t ws_size,
                              hipStream_t stream){
  const float* x   = (const float*)d_in[0];
  const int*   ei  = (const int*)d_in[1];
  const int*   esrc = ei;
  const int*   edst = ei + EE;
  const float* W1  = (const float*)d_in[2];
  const float* as1 = (const float*)d_in[3];
  const float* ad1 = (const float*)d_in[4];
  const float* b1  = (const float*)d_in[5];
  const float* W2  = (const float*)d_in[6];
  const float* as2 = (const float*)d_in[7];
  const float* ad2 = (const float*)d_in[8];
  const float* b2  = (const float*)d_in[9];
  const float* W3  = (const float*)d_in[10];
  const float* as3 = (const float*)d_in[11];
  const float* ad3 = (const float*)d_in[12];
  const float* b3  = (const float*)d_in[13];
  float* out = (float*)d_out;

  char* w = (char*)d_ws;
  size_t off = 0;
  auto alloc = [&](size_t bytes)->char*{
    char* p = w + off;
    off = (off + bytes + 255) & ~(size_t)255;
    return p;
  };
  ushortT*  xb   = (ushortT*)alloc((size_t)NN*512*2);
  ushortT*  fA   = (ushortT*)alloc((size_t)NN*512*2);
  ushortT*  fB   = (ushortT*)alloc((size_t)NN*512*2);
  ushortT*  h3b  = (ushortT*)alloc((size_t)NN*40*2);
  ushortT*  Wt1  = (ushortT*)alloc((size_t)512*512*2);
  ushortT*  Wt2  = (ushortT*)alloc((size_t)512*512*2);
  ushortT*  Wt3p = (ushortT*)alloc((size_t)64*48*8*2);
  float*    a_s  = (float*)alloc((size_t)NN*8*4);
  float*    a_d  = (float*)alloc((size_t)NN*8*4);
  unsigned* rec  = (unsigned*)alloc((size_t)8*ETOT*4);
  int* rowstart  = (int*)alloc((size_t)(NN+1)*4);
  int* cursor    = (int*)alloc((size_t)NN*4);
  int* counts    = (int*)alloc((size_t)NN*4);
  int* srcs      = (int*)alloc((size_t)ETOT*4);
  int* edsts     = (int*)alloc((size_t)ETOT*4);

  // ---- fused conversions (independent of CSR) ----
  k_prep<<<10608, 256, 0, stream>>>(x, xb, W1, Wt1, W2, Wt2, W3, Wt3p);

  // ---- CSR build (dst-grouped) ----
  hipMemsetAsync(counts, 0, (size_t)NN*4, stream);
  hipMemsetAsync(cursor, 0, (size_t)NN*4, stream);
  k_count<<<(ETOT+255)/256, 256, 0, stream>>>(edst, counts);
  k_scan<<<1, 1024, 0, stream>>>(counts, rowstart);
  k_fill<<<(ETOT+255)/256, 256, 0, stream>>>(esrc, edst, rowstart, cursor, srcs, edsts);

  dim3 mgrid((NN+127)/128, 4);
  int edge_blocks = (ETOT + 255)/256;
  int agg_blocks  = ((NN + 63)/64)*8;

  // ---- layer 1 ----
  k_gemm_bf16<<<mgrid, 256, 0, stream>>>(xb, Wt1, fA, NN);
  k_attn8<<<(NN+3)/4, 256, 0, stream>>>(fA, as1, ad1, a_s, a_d);
  k_edge_pre<<<edge_blocks, 256, 0, stream>>>(srcs, edsts, a_s, a_d, rec);
  k_agg512<<<agg_blocks, 512, 0, stream>>>(fA, rec, rowstart, b1, fB);

  // ---- layer 2 ----
  k_gemm_bf16<<<mgrid, 256, 0, stream>>>(fB, Wt2, fA, NN);
  k_attn8<<<(NN+3)/4, 256, 0, stream>>>(fA, as2, ad2, a_s, a_d);
  k_edge_pre<<<edge_blocks, 256, 0, stream>>>(srcs, edsts, a_s, a_d, rec);
  k_agg512<<<agg_blocks, 512, 0, stream>>>(fA, rec, rowstart, b2, fB);

  // ---- layer 3 ----
  k_gemm3m<<<(NN+127)/128, 256, 0, stream>>>(fB, Wt3p, h3b, NN);
  k_attn1b<<<(NN+3)/4, 256, 0, stream>>>(h3b, as3, ad3, a_s, a_d);
  k_agg_l3<<<NN, 64, 0, stream>>>(h3b, a_s, a_d, rowstart, srcs, b3, out);
}